// Round 6
// baseline (1203.041 us; speedup 1.0000x reference)
//
#include <hip/hip_runtime.h>
#include <cstdint>
#include <cstddef>

// B=8, C=256/128, H=W=128. Padded NHWC bf16 tensors: [n][130][130][C], pad ring = 0.
// elem(n,h,w,c) = ((n*130 + h+1)*130 + (w+1))*C + c

typedef float  f32x4 __attribute__((ext_vector_type(4)));
typedef float  f4v   __attribute__((ext_vector_type(4)));
typedef short  s16x8 __attribute__((ext_vector_type(8)));
typedef unsigned short u16x4 __attribute__((ext_vector_type(4)));

__device__ __forceinline__ float bf2f(unsigned short u) {
    unsigned x = ((unsigned)u) << 16;
    return __builtin_bit_cast(float, x);
}
__device__ __forceinline__ unsigned short f2bf(float f) {
    unsigned u = __builtin_bit_cast(unsigned, f);
    unsigned r = (u + 0x7fffu + ((u >> 16) & 1u)) >> 16;
    return (unsigned short)r;
}

#define GL_LDS(gp, lp) __builtin_amdgcn_global_load_lds( \
    (const __attribute__((address_space(1))) unsigned int*)(const void*)(gp), \
    (__attribute__((address_space(3))) unsigned int*)(void*)(lp), 16, 0, 0)

// ---------------------------------------------------------------------------
// VARIANT m4p4 (baseline control): wave = 64oc x 64px. 4 blocks/CU.
// block 256 thr = 4 waves; tile 2 rows x 64 cols x 128 oc.
// grid ((COUT/128)*2 [octile*2+wtile], 64 h-pairs, 8 n)
// ---------------------------------------------------------------------------
template<int CIN, int COUT, bool RELU, bool OUTF32>
__global__ __launch_bounds__(256, 4)
void conv3_m4p4(const unsigned short* __restrict__ in,
                const unsigned short* __restrict__ wpk,
                const float* __restrict__ sc, const float* __restrict__ bi,
                void* __restrict__ outv)
{
    __shared__ unsigned short lds[2][8704];      // 2 x 17408 B
    const int tid  = threadIdx.x;
    const int lane = tid & 63;
    const int wv   = tid >> 6;
    const int c    = lane & 15;
    const int g    = lane >> 4;
    const int gx     = blockIdx.x;
    const int wtile  = gx & 1;
    const int octile = gx >> 1;
    const int h0   = blockIdx.y * 2;
    const int n    = blockIdx.z;
    const int w0   = wtile * 64;
    const int r    = wv >> 1;
    const int ocbase = octile * 128 + (wv & 1) * 64;
    const int ocf0   = octile * 8 + (wv & 1) * 4;

    int addrB[3];
    #pragma unroll
    for (int kx = 0; kx < 3; ++kx) {
        int ps0 = c + kx;
        addrB[kx] = r * 4224 + ps0 * 64 + ((g ^ ((ps0 >> 1) & 3)) << 4);
    }

    int so[5];
    #pragma unroll
    for (int it = 0; it < 5; ++it) {
        int u   = it * 256 + tid;
        int row = u / 264;
        int rem = u - row * 264;
        int ps  = rem >> 2;
        int s   = rem & 3;
        int icq = s ^ ((ps >> 1) & 3);
        so[it] = ((n * 130 + h0 + row) * 130 + (w0 + ps)) * CIN + icq * 8;
    }

    auto STAGE = [&](int chunk, int bsel) {
        const unsigned short* bp = in + chunk * 32;
        char* lb = (char*)lds + bsel * 17408 + tid * 16;
        #pragma unroll
        for (int it = 0; it < 4; ++it)
            GL_LDS(bp + so[it], lb + it * 4096);
        if (wv == 0)
            GL_LDS(bp + so[4], lb + 16384);
    };

    f32x4 acc[4][4];
    #pragma unroll
    for (int m = 0; m < 4; ++m)
        #pragma unroll
        for (int p = 0; p < 4; ++p) acc[m][p] = 0.0f;

    const int NC = CIN / 32;
    STAGE(0, 0);
    __syncthreads();

    for (int chunk = 0; chunk < NC; ++chunk) {
        const int cur = chunk & 1;
        if (chunk + 1 < NC) STAGE(chunk + 1, cur ^ 1);
        const char* lb = (const char*)lds + cur * 17408;
        #pragma unroll
        for (int kk = 0; kk < 9; ++kk) {
            const int ky = kk / 3, kx = kk % 3;
            s16x8 af[4], bf[4];
            #pragma unroll
            for (int m = 0; m < 4; ++m)
                af[m] = *(const s16x8*)(wpk
                    + ((size_t)((chunk * 9 + kk) * (COUT / 16) + ocf0 + m)) * 512 + lane * 8);
            #pragma unroll
            for (int p = 0; p < 4; ++p)
                bf[p] = *(const s16x8*)(lb + addrB[kx] + ky * 4224 + p * 1024);
            #pragma unroll
            for (int m = 0; m < 4; ++m)
                #pragma unroll
                for (int p = 0; p < 4; ++p)
                    acc[m][p] = __builtin_amdgcn_mfma_f32_16x16x32_bf16(af[m], bf[p], acc[m][p], 0, 0, 0);
        }
        __syncthreads();
    }

    #pragma unroll
    for (int m = 0; m < 4; ++m) {
        const int oc4 = ocbase + m * 16 + g * 4;
        const f4v s4 = *(const f4v*)(sc + oc4);
        const f4v b4 = *(const f4v*)(bi + oc4);
        #pragma unroll
        for (int p = 0; p < 4; ++p) {
            const int w = w0 + p * 16 + c;
            float y[4];
            #pragma unroll
            for (int j = 0; j < 4; ++j) {
                y[j] = acc[m][p][j] * s4[j] + b4[j];
                if (RELU) y[j] = fmaxf(y[j], 0.0f);
            }
            if (OUTF32) {
                float* op = (float*)outv + (((size_t)n * COUT + oc4) << 14) + ((h0 + r) << 7) + w;
                op[0] = y[0]; op[16384] = y[1]; op[32768] = y[2]; op[49152] = y[3];
            } else {
                u16x4 pk;
                #pragma unroll
                for (int j = 0; j < 4; ++j) pk[j] = f2bf(y[j]);
                *(u16x4*)((unsigned short*)outv
                    + ((size_t)(n * 130 + h0 + r + 1) * 130 + w + 1) * COUT + oc4) = pk;
            }
        }
    }
}

// ---------------------------------------------------------------------------
// VARIANT m4p8 (A-traffic halved): wave = 64oc x 128px (full row). 2 blocks/CU.
// block 256 thr = 4 waves (r, och); tile 2 rows x 128 cols x 128 oc.
// LDS: 4 rows x 130 px x 32 ic packed (row stride 8320 B) = 33280 B x2 dbuf.
// grid (COUT/128, 64 h-pairs, 8 n)
// ---------------------------------------------------------------------------
template<int CIN, int COUT, bool RELU, bool OUTF32>
__global__ __launch_bounds__(256, 2)
void conv3_m4p8(const unsigned short* __restrict__ in,
                const unsigned short* __restrict__ wpk,
                const float* __restrict__ sc, const float* __restrict__ bi,
                void* __restrict__ outv)
{
    __shared__ unsigned short lds[2][16640];     // 2 x 33280 B
    const int tid  = threadIdx.x;
    const int lane = tid & 63;
    const int wv   = tid >> 6;
    const int c    = lane & 15;
    const int g    = lane >> 4;
    const int h0   = blockIdx.y * 2;
    const int n    = blockIdx.z;
    const int r    = wv >> 1;                    // output row 0/1
    const int och  = wv & 1;                     // oc half
    const int ocbase = blockIdx.x * 128 + och * 64;
    const int ocf0   = blockIdx.x * 8 + och * 4;

    // B-read base: ps = 16p + c + kx; XOR term p-independent (16p>>1 = 8p ≡ 0 mod 4)
    int addrB[3];
    #pragma unroll
    for (int kx = 0; kx < 3; ++kx) {
        int ps0 = c + kx;
        addrB[kx] = r * 8320 + ps0 * 64 + ((g ^ ((ps0 >> 1) & 3)) << 4);
    }

    // staging: 4 rows x 130 px x 4 units = 2080 units; u = it*256+tid; dst = u*16 (packed)
    int so[9];
    #pragma unroll
    for (int it = 0; it < 9; ++it) {
        int u   = it * 256 + tid;
        int row = u / 520;
        int rem = u - row * 520;
        int ps  = rem >> 2;
        int s   = rem & 3;
        int icq = s ^ ((ps >> 1) & 3);
        so[it] = ((n * 130 + h0 + row) * 130 + ps) * CIN + icq * 8;
    }

    auto STAGE = [&](int chunk, int bsel) {
        const unsigned short* bp = in + chunk * 32;
        char* lb = (char*)lds + bsel * 33280 + tid * 16;
        #pragma unroll
        for (int it = 0; it < 8; ++it)
            GL_LDS(bp + so[it], lb + it * 4096);
        if (tid < 32)
            GL_LDS(bp + so[8], lb + 32768);
    };

    f32x4 acc[4][8];
    #pragma unroll
    for (int m = 0; m < 4; ++m)
        #pragma unroll
        for (int p = 0; p < 8; ++p) acc[m][p] = 0.0f;

    const int NC = CIN / 32;
    STAGE(0, 0);
    __syncthreads();

    for (int chunk = 0; chunk < NC; ++chunk) {
        const int cur = chunk & 1;
        if (chunk + 1 < NC) STAGE(chunk + 1, cur ^ 1);
        const char* lb = (const char*)lds + cur * 33280;
        #pragma unroll
        for (int kk = 0; kk < 9; ++kk) {
            const int ky = kk / 3, kx = kk % 3;
            s16x8 af[4], bf[8];
            #pragma unroll
            for (int m = 0; m < 4; ++m)
                af[m] = *(const s16x8*)(wpk
                    + ((size_t)((chunk * 9 + kk) * (COUT / 16) + ocf0 + m)) * 512 + lane * 8);
            #pragma unroll
            for (int p = 0; p < 8; ++p)
                bf[p] = *(const s16x8*)(lb + addrB[kx] + ky * 8320 + p * 1024);
            #pragma unroll
            for (int m = 0; m < 4; ++m)
                #pragma unroll
                for (int p = 0; p < 8; ++p)
                    acc[m][p] = __builtin_amdgcn_mfma_f32_16x16x32_bf16(af[m], bf[p], acc[m][p], 0, 0, 0);
        }
        __syncthreads();
    }

    #pragma unroll
    for (int m = 0; m < 4; ++m) {
        const int oc4 = ocbase + m * 16 + g * 4;
        const f4v s4 = *(const f4v*)(sc + oc4);
        const f4v b4 = *(const f4v*)(bi + oc4);
        #pragma unroll
        for (int p = 0; p < 8; ++p) {
            const int w = p * 16 + c;
            float y[4];
            #pragma unroll
            for (int j = 0; j < 4; ++j) {
                y[j] = acc[m][p][j] * s4[j] + b4[j];
                if (RELU) y[j] = fmaxf(y[j], 0.0f);
            }
            if (OUTF32) {
                float* op = (float*)outv + (((size_t)n * COUT + oc4) << 14) + ((h0 + r) << 7) + w;
                op[0] = y[0]; op[16384] = y[1]; op[32768] = y[2]; op[49152] = y[3];
            } else {
                u16x4 pk;
                #pragma unroll
                for (int j = 0; j < 4; ++j) pk[j] = f2bf(y[j]);
                *(u16x4*)((unsigned short*)outv
                    + ((size_t)(n * 130 + h0 + r + 1) * 130 + w + 1) * COUT + oc4) = pk;
            }
        }
    }
}

// ---------------------------------------------------------------------------
// VARIANT m8p4 (B-LDS-traffic halved): wave = 128oc x 64px. 2 blocks/CU.
// block 256 thr = 4 waves (r, och); tile 2 rows x 64 cols x 256 oc.
// Staging identical to m4p4 (17408 B x2). grid ((COUT/256)*2, 64, 8)
// ---------------------------------------------------------------------------
template<int CIN, bool RELU, bool OUTF32>
__global__ __launch_bounds__(256, 2)
void conv3_m8p4(const unsigned short* __restrict__ in,
                const unsigned short* __restrict__ wpk,
                const float* __restrict__ sc, const float* __restrict__ bi,
                void* __restrict__ outv)
{
    const int COUT = 256;
    __shared__ unsigned short lds[2][8704];
    const int tid  = threadIdx.x;
    const int lane = tid & 63;
    const int wv   = tid >> 6;
    const int c    = lane & 15;
    const int g    = lane >> 4;
    const int gx     = blockIdx.x;
    const int wtile  = gx & 1;
    const int octile = gx >> 1;
    const int h0   = blockIdx.y * 2;
    const int n    = blockIdx.z;
    const int w0   = wtile * 64;
    const int r    = wv >> 1;
    const int och  = wv & 1;
    const int ocbase = octile * 256 + och * 128;
    const int ocf0   = octile * 16 + och * 8;

    int addrB[3];
    #pragma unroll
    for (int kx = 0; kx < 3; ++kx) {
        int ps0 = c + kx;
        addrB[kx] = r * 4224 + ps0 * 64 + ((g ^ ((ps0 >> 1) & 3)) << 4);
    }

    int so[5];
    #pragma unroll
    for (int it = 0; it < 5; ++it) {
        int u   = it * 256 + tid;
        int row = u / 264;
        int rem = u - row * 264;
        int ps  = rem >> 2;
        int s   = rem & 3;
        int icq = s ^ ((ps >> 1) & 3);
        so[it] = ((n * 130 + h0 + row) * 130 + (w0 + ps)) * CIN + icq * 8;
    }

    auto STAGE = [&](int chunk, int bsel) {
        const unsigned short* bp = in + chunk * 32;
        char* lb = (char*)lds + bsel * 17408 + tid * 16;
        #pragma unroll
        for (int it = 0; it < 4; ++it)
            GL_LDS(bp + so[it], lb + it * 4096);
        if (wv == 0)
            GL_LDS(bp + so[4], lb + 16384);
    };

    f32x4 acc[8][4];
    #pragma unroll
    for (int m = 0; m < 8; ++m)
        #pragma unroll
        for (int p = 0; p < 4; ++p) acc[m][p] = 0.0f;

    const int NC = CIN / 32;
    STAGE(0, 0);
    __syncthreads();

    for (int chunk = 0; chunk < NC; ++chunk) {
        const int cur = chunk & 1;
        if (chunk + 1 < NC) STAGE(chunk + 1, cur ^ 1);
        const char* lb = (const char*)lds + cur * 17408;
        #pragma unroll
        for (int kk = 0; kk < 9; ++kk) {
            const int ky = kk / 3, kx = kk % 3;
            s16x8 af[8], bf[4];
            #pragma unroll
            for (int m = 0; m < 8; ++m)
                af[m] = *(const s16x8*)(wpk
                    + ((size_t)((chunk * 9 + kk) * (COUT / 16) + ocf0 + m)) * 512 + lane * 8);
            #pragma unroll
            for (int p = 0; p < 4; ++p)
                bf[p] = *(const s16x8*)(lb + addrB[kx] + ky * 4224 + p * 1024);
            #pragma unroll
            for (int m = 0; m < 8; ++m)
                #pragma unroll
                for (int p = 0; p < 4; ++p)
                    acc[m][p] = __builtin_amdgcn_mfma_f32_16x16x32_bf16(af[m], bf[p], acc[m][p], 0, 0, 0);
        }
        __syncthreads();
    }

    #pragma unroll
    for (int m = 0; m < 8; ++m) {
        const int oc4 = ocbase + m * 16 + g * 4;
        const f4v s4 = *(const f4v*)(sc + oc4);
        const f4v b4 = *(const f4v*)(bi + oc4);
        #pragma unroll
        for (int p = 0; p < 4; ++p) {
            const int w = w0 + p * 16 + c;
            float y[4];
            #pragma unroll
            for (int j = 0; j < 4; ++j) {
                y[j] = acc[m][p][j] * s4[j] + b4[j];
                if (RELU) y[j] = fmaxf(y[j], 0.0f);
            }
            if (OUTF32) {
                float* op = (float*)outv + (((size_t)n * COUT + oc4) << 14) + ((h0 + r) << 7) + w;
                op[0] = y[0]; op[16384] = y[1]; op[32768] = y[2]; op[49152] = y[3];
            } else {
                u16x4 pk;
                #pragma unroll
                for (int j = 0; j < 4; ++j) pk[j] = f2bf(y[j]);
                *(u16x4*)((unsigned short*)outv
                    + ((size_t)(n * 130 + h0 + r + 1) * 130 + w + 1) * COUT + oc4) = pk;
            }
        }
    }
}

// ---------------------------------------------------------------------------
// conv1x1 + BN affine fused residual add + ReLU, in-place on io (bf16 NHWC pad).
// ---------------------------------------------------------------------------
__global__ __launch_bounds__(256, 2)
void conv1_mfma(const unsigned short* __restrict__ xb,
                const unsigned short* __restrict__ w1pk,
                const float* __restrict__ sc, const float* __restrict__ bi,
                unsigned short* __restrict__ io)
{
    const int tid  = threadIdx.x;
    const int h    = blockIdx.y;
    const int n    = blockIdx.z;
    const int lane = tid & 63;
    const int wv   = tid >> 6;
    const int c    = lane & 15;
    const int g    = lane >> 4;
    const int pixbase = (wv >> 1) * 64;
    const int ocbase  = blockIdx.x * 128 + (wv & 1) * 64;
    const int ocf0    = blockIdx.x * 8 + (wv & 1) * 4;
    const size_t pixrow = ((size_t)(n * 130 + h + 1) * 130 + (pixbase + c + 1)) * 256;

    f32x4 acc[4][4];
    #pragma unroll
    for (int m = 0; m < 4; ++m)
        #pragma unroll
        for (int p = 0; p < 4; ++p) acc[m][p] = 0.0f;

    s16x8 a0[4], b0[4], a1[4], b1[4];

#define LOADC(ck, A, B) do {                                                        \
    _Pragma("unroll") for (int p = 0; p < 4; ++p)                                   \
        B[p] = *(const s16x8*)(xb + pixrow + (size_t)(16 * p) * 256 + (ck) * 32 + g * 8); \
    _Pragma("unroll") for (int m = 0; m < 4; ++m)                                   \
        A[m] = *(const s16x8*)(w1pk + ((size_t)((ck) * 16 + ocf0 + m)) * 512 + lane * 8); \
} while (0)
#define MM(A, B)                                                                    \
    _Pragma("unroll") for (int m = 0; m < 4; ++m)                                   \
        _Pragma("unroll") for (int p = 0; p < 4; ++p)                               \
            acc[m][p] = __builtin_amdgcn_mfma_f32_16x16x32_bf16(A[m], B[p], acc[m][p], 0, 0, 0)

    LOADC(0, a0, b0);
    #pragma unroll
    for (int ck = 0; ck < 8; ++ck) {
        if ((ck & 1) == 0) { if (ck < 7) LOADC(ck + 1, a1, b1); MM(a0, b0); }
        else               { if (ck < 7) LOADC(ck + 1, a0, b0); MM(a1, b1); }
    }
#undef LOADC
#undef MM

    #pragma unroll
    for (int m = 0; m < 4; ++m) {
        const int oc4 = ocbase + m * 16 + g * 4;
        const f4v s4 = *(const f4v*)(sc + oc4);
        const f4v b4 = *(const f4v*)(bi + oc4);
        #pragma unroll
        for (int p = 0; p < 4; ++p) {
            const int pix = pixbase + p * 16 + c;
            size_t idx = ((size_t)(n * 130 + h + 1) * 130 + pix + 1) * 256 + oc4;
            u16x4 old = *(const u16x4*)(io + idx);
            u16x4 pk;
            #pragma unroll
            for (int j = 0; j < 4; ++j) {
                float y = acc[m][p][j] * s4[j] + b4[j] + bf2f(old[j]);
                pk[j] = f2bf(fmaxf(y, 0.0f));
            }
            *(u16x4*)(io + idx) = pk;
        }
    }
}

// ---------------------------------------------------------------------------
template<bool REV>
__global__ __launch_bounds__(128)
void pool_h_k(unsigned short* __restrict__ p)
{
    const int n = blockIdx.x >> 7, w = blockIdx.x & 127, cth = threadIdx.x;
    unsigned short* base = p + (((size_t)n * 130 + 1) * 130 + (w + 1)) * 128 + cth;
    const int stride = 130 * 128;
    float m = -3.402823466e+38f;
    for (int i = 0; i < 128; ++i) {
        int hh = REV ? (127 - i) : i;
        unsigned short* q = base + (size_t)hh * stride;
        m = fmaxf(m, bf2f(*q));
        *q = f2bf(m);
    }
}

template<bool REV>
__global__ __launch_bounds__(128)
void pool_w_add_k(const unsigned short* __restrict__ lsrc,
                  unsigned short* __restrict__ tdst)
{
    const int n = blockIdx.x >> 7, hh = blockIdx.x & 127, cth = threadIdx.x;
    const size_t rowbase = ((size_t)(n * 130 + hh + 1) * 130) * 128 + cth;
    float m = -3.402823466e+38f;
    for (int i = 0; i < 128; ++i) {
        int w = REV ? (127 - i) : i;
        size_t off = rowbase + (size_t)(w + 1) * 128;
        m = fmaxf(m, bf2f(lsrc[off]));
        tdst[off] = f2bf(m + bf2f(tdst[off]));
    }
}

// ---------------------------------------------------------------------------
__global__ __launch_bounds__(256)
void padzero_k(unsigned short* __restrict__ t, int C)
{
    int idx = blockIdx.x * 256 + threadIdx.x;
    int n = blockIdx.y;
    int cpu = C >> 3;
    if (idx >= 516 * cpu) return;
    int cell = idx / cpu, cq = idx - cell * cpu;
    int h, w;
    if (cell < 260) { h = (cell < 130) ? -1 : 128; w = (cell % 130) - 1; }
    else { int j = cell - 260; w = (j < 128) ? -1 : 128; h = j & 127; }
    size_t off = (((size_t)n * 130 + h + 1) * 130 + (w + 1)) * C + cq * 8;
    uint4 z; z.x = 0; z.y = 0; z.z = 0; z.w = 0;
    *(uint4*)(t + off) = z;
}

// ---------------------------------------------------------------------------
__global__ __launch_bounds__(256)
void transform_x_k(const float* __restrict__ x, unsigned short* __restrict__ xb)
{
    __shared__ float sm[64][132];
    const int h = blockIdx.x, n = blockIdx.y, t = threadIdx.x;
    for (int cc0 = 0; cc0 < 256; cc0 += 64) {
        __syncthreads();
        {
            int ci = t >> 7, wi = t & 127;
            #pragma unroll 8
            for (int k = 0; k < 32; ++k)
                sm[ci + 2 * k][wi] = x[((size_t)(n * 256 + cc0 + ci + 2 * k) << 14) + (h << 7) + wi];
        }
        __syncthreads();
        {
            int wi = t >> 1, cq = t & 1;
            unsigned short tmp[32];
            #pragma unroll
            for (int m2 = 0; m2 < 32; ++m2) tmp[m2] = f2bf(sm[cq * 32 + m2][wi]);
            unsigned short* dst = xb + (((size_t)n * 130 + h + 1) * 130 + wi + 1) * 256 + cc0 + cq * 32;
            #pragma unroll
            for (int q = 0; q < 4; ++q) *(uint4*)(dst + q * 8) = *(const uint4*)(tmp + q * 8);
        }
    }
}

// ---------------------------------------------------------------------------
__global__ __launch_bounds__(256)
void prepack3_k(const float* __restrict__ w, unsigned short* __restrict__ dst,
                int CIN, int COUT)
{
    int idx = blockIdx.x * 256 + threadIdx.x;
    if (idx >= COUT * CIN * 9) return;
    int kk = idx % 9; int rest = idx / 9;
    int ic = rest % CIN; int oc = rest / CIN;
    float v = w[(size_t)(oc * CIN + ic) * 9 + kk];
    int chunk = ic >> 5, icr = ic & 31, gg = icr >> 3, j = icr & 7;
    int m = oc >> 4, ocr = oc & 15, ln = gg * 16 + ocr;
    size_t off = ((size_t)((chunk * 9 + kk) * (COUT / 16) + m)) * 512 + ln * 8 + j;
    dst[off] = f2bf(v);
}

__global__ __launch_bounds__(256)
void prepack1_k(const float* __restrict__ w, unsigned short* __restrict__ dst)
{
    int idx = blockIdx.x * 256 + threadIdx.x;
    if (idx >= 65536) return;
    int ic = idx & 255, oc = idx >> 8;
    float v = w[oc * 256 + ic];
    int chunk = ic >> 5, icr = ic & 31, gg = icr >> 3, j = icr & 7;
    int m = oc >> 4, ocr = oc & 15, ln = gg * 16 + ocr;
    size_t off = ((size_t)(chunk * 16 + m)) * 512 + ln * 8 + j;
    dst[off] = f2bf(v);
}

// ---------------------------------------------------------------------------
extern "C" void kernel_launch(void* const* d_in, const int* in_sizes, int n_in,
                              void* d_out, int out_size, void* d_ws, size_t ws_size,
                              hipStream_t stream)
{
    const float* x     = (const float*)d_in[0];
    const float* w_t   = (const float*)d_in[1];
    const float* s_t   = (const float*)d_in[2];
    const float* b_t   = (const float*)d_in[3];
    const float* w_l   = (const float*)d_in[4];
    const float* s_l   = (const float*)d_in[5];
    const float* b_l   = (const float*)d_in[6];
    const float* w_b   = (const float*)d_in[7];
    const float* s_b   = (const float*)d_in[8];
    const float* b_b   = (const float*)d_in[9];
    const float* w_r   = (const float*)d_in[10];
    const float* s_r   = (const float*)d_in[11];
    const float* b_r   = (const float*)d_in[12];
    const float* w_tl3 = (const float*)d_in[13];
    const float* s_tl3 = (const float*)d_in[14];
    const float* b_tl3 = (const float*)d_in[15];
    const float* w_br3 = (const float*)d_in[16];
    const float* s_br3 = (const float*)d_in[17];
    const float* b_br3 = (const float*)d_in[18];
    const float* w_tl1 = (const float*)d_in[19];
    const float* s_tl1 = (const float*)d_in[20];
    const float* b_tl1 = (const float*)d_in[21];
    const float* w_br1 = (const float*)d_in[22];
    const float* s_br1 = (const float*)d_in[23];
    const float* b_br1 = (const float*)d_in[24];
    const float* w_tlo = (const float*)d_in[25];
    const float* s_tlo = (const float*)d_in[26];
    const float* b_tlo = (const float*)d_in[27];
    const float* w_bro = (const float*)d_in[28];
    const float* s_bro = (const float*)d_in[29];
    const float* b_bro = (const float*)d_in[30];

    typedef unsigned short ush;
    const size_t T256 = (size_t)8 * 130 * 130 * 256;
    const size_t T128 = (size_t)8 * 130 * 130 * 128;

    ush* xb = (ush*)d_ws;
    ush* tt = xb + T256;
    ush* bb = tt + T128;
    ush* ll = bb + T128;
    ush* rr = ll + T128;
    ush* wq = rr + T128;
    ush* wp_t   = wq;
    ush* wp_l   = wp_t   + 294912;
    ush* wp_b   = wp_l   + 294912;
    ush* wp_r   = wp_b   + 294912;
    ush* wp_tl3 = wp_r   + 294912;
    ush* wp_br3 = wp_tl3 + 294912;
    ush* wp_tlo = wp_br3 + 294912;
    ush* wp_bro = wp_tlo + 589824;
    ush* wp_tl1 = wp_bro + 589824;
    ush* wp_br1 = wp_tl1 + 65536;
    ush* tl = ll;

    prepack3_k<<<dim3((294912 + 255) / 256), dim3(256), 0, stream>>>(w_t,   wp_t,   256, 128);
    prepack3_k<<<dim3((294912 + 255) / 256), dim3(256), 0, stream>>>(w_l,   wp_l,   256, 128);
    prepack3_k<<<dim3((294912 + 255) / 256), dim3(256), 0, stream>>>(w_b,   wp_b,   256, 128);
    prepack3_k<<<dim3((294912 + 255) / 256), dim3(256), 0, stream>>>(w_r,   wp_r,   256, 128);
    prepack3_k<<<dim3((294912 + 255) / 256), dim3(256), 0, stream>>>(w_tl3, wp_tl3, 128, 256);
    prepack3_k<<<dim3((294912 + 255) / 256), dim3(256), 0, stream>>>(w_br3, wp_br3, 128, 256);
    prepack3_k<<<dim3((589824 + 255) / 256), dim3(256), 0, stream>>>(w_tlo, wp_tlo, 256, 256);
    prepack3_k<<<dim3((589824 + 255) / 256), dim3(256), 0, stream>>>(w_bro, wp_bro, 256, 256);
    prepack1_k<<<dim3(256), dim3(256), 0, stream>>>(w_tl1, wp_tl1);
    prepack1_k<<<dim3(256), dim3(256), 0, stream>>>(w_br1, wp_br1);

    padzero_k<<<dim3(66, 8), dim3(256), 0, stream>>>(xb, 256);
    padzero_k<<<dim3(33, 8), dim3(256), 0, stream>>>(tt, 128);
    padzero_k<<<dim3(33, 8), dim3(256), 0, stream>>>(bb, 128);
    padzero_k<<<dim3(33, 8), dim3(256), 0, stream>>>(ll, 128);
    padzero_k<<<dim3(33, 8), dim3(256), 0, stream>>>(rr, 128);

    transform_x_k<<<dim3(128, 8), dim3(256), 0, stream>>>(x, xb);

    // stage A: t,l = m4p4 control; b,r = m4p8 variant (identical shape -> A/B)
    conv3_m4p4<256, 128, true, false><<<dim3(2, 64, 8), dim3(256), 0, stream>>>(xb, wp_t, s_t, b_t, tt);
    conv3_m4p4<256, 128, true, false><<<dim3(2, 64, 8), dim3(256), 0, stream>>>(xb, wp_l, s_l, b_l, ll);
    conv3_m4p8<256, 128, true, false><<<dim3(1, 64, 8), dim3(256), 0, stream>>>(xb, wp_b, s_b, b_b, bb);
    conv3_m4p8<256, 128, true, false><<<dim3(1, 64, 8), dim3(256), 0, stream>>>(xb, wp_r, s_r, b_r, rr);

    pool_h_k<true ><<<dim3(1024), dim3(128), 0, stream>>>(tt);
    pool_h_k<false><<<dim3(1024), dim3(128), 0, stream>>>(bb);
    pool_w_add_k<true ><<<dim3(1024), dim3(128), 0, stream>>>(ll, tt);
    pool_w_add_k<false><<<dim3(1024), dim3(128), 0, stream>>>(rr, bb);

    // tl chain: tl3/tlo = m4p8 ; br chain: br3/bro = m8p4 (identical shapes -> A/B)
    padzero_k<<<dim3(66, 8), dim3(256), 0, stream>>>(tl, 256);
    conv3_m4p8<128, 256, false, false><<<dim3(2, 64, 8), dim3(256), 0, stream>>>(tt, wp_tl3, s_tl3, b_tl3, tl);
    conv1_mfma<<<dim3(2, 128, 8), dim3(256), 0, stream>>>(xb, wp_tl1, s_tl1, b_tl1, tl);
    conv3_m4p8<256, 256, true, true><<<dim3(2, 64, 8), dim3(256), 0, stream>>>(tl, wp_tlo, s_tlo, b_tlo, d_out);

    conv3_m8p4<128, false, false><<<dim3(2, 64, 8), dim3(256), 0, stream>>>(bb, wp_br3, s_br3, b_br3, tl);
    conv1_mfma<<<dim3(2, 128, 8), dim3(256), 0, stream>>>(xb, wp_br1, s_br1, b_br1, tl);
    conv3_m8p4<256, true, true><<<dim3(2, 64, 8), dim3(256), 0, stream>>>(tl, wp_bro, s_bro, b_bro,
                                                                          (float*)d_out + 33554432);
}

// Round 7
// 1002.471 us; speedup vs baseline: 1.2001x; 1.2001x over previous
//
#include <hip/hip_runtime.h>
#include <cstdint>
#include <cstddef>

// B=8, C=256/128, H=W=128. Padded NHWC bf16 tensors: [n][130][130][C], pad ring = 0.
// elem(n,h,w,c) = ((n*130 + h+1)*130 + (w+1))*C + c

typedef float  f32x4 __attribute__((ext_vector_type(4)));
typedef float  f4v   __attribute__((ext_vector_type(4)));
typedef short  s16x8 __attribute__((ext_vector_type(8)));
typedef unsigned short u16x4 __attribute__((ext_vector_type(4)));

__device__ __forceinline__ float bf2f(unsigned short u) {
    unsigned x = ((unsigned)u) << 16;
    return __builtin_bit_cast(float, x);
}
__device__ __forceinline__ unsigned short f2bf(float f) {
    unsigned u = __builtin_bit_cast(unsigned, f);
    unsigned r = (u + 0x7fffu + ((u >> 16) & 1u)) >> 16;
    return (unsigned short)r;
}

#define GL_LDS(gp, lp) __builtin_amdgcn_global_load_lds( \
    (const __attribute__((address_space(1))) unsigned int*)(const void*)(gp), \
    (__attribute__((address_space(3))) unsigned int*)(void*)(lp), 16, 0, 0)

// ---------------------------------------------------------------------------
// conv3x3 + BN affine (+opt ReLU), bf16 MFMA implicit GEMM. m4p4 geometry
// (round-5 proven best: 4 blocks/CU): wave = 64oc x 64px; block = 4 waves,
// tile 2 rows x 64 cols x 128 oc. 2-phase dbuf pipeline, 1 barrier/chunk.
// SWZ: bijective XCD swizzle (T1) — blocks on one XCD get a contiguous
// (gx, h-band) range for L2 row reuse. grid ((COUT/128)*2, 64, 8).
// ---------------------------------------------------------------------------
template<int CIN, int COUT, bool RELU, bool OUTF32, bool SWZ>
__global__ __launch_bounds__(256, 4)
void conv3_mfma(const unsigned short* __restrict__ in,
                const unsigned short* __restrict__ wpk,
                const float* __restrict__ sc, const float* __restrict__ bi,
                void* __restrict__ outv)
{
    __shared__ unsigned short lds[2][8704];      // 2 x 17408 B
    const int tid  = threadIdx.x;
    const int lane = tid & 63;
    const int wv   = tid >> 6;
    const int c    = lane & 15;
    const int g    = lane >> 4;

    constexpr int GX  = (COUT / 128) * 2;
    int gx, hy, n;
    if (SWZ) {
        constexpr int NWG = GX * 64 * 8;
        constexpr int Q   = NWG / 8;
        const int braw = blockIdx.x + GX * (blockIdx.y + 64 * blockIdx.z);
        const int wl   = (braw & 7) * Q + (braw >> 3);
        gx = wl % GX;
        const int rest = wl / GX;
        hy = rest & 63;
        n  = rest >> 6;
    } else {
        gx = blockIdx.x; hy = blockIdx.y; n = blockIdx.z;
    }
    const int wtile  = gx & 1;
    const int octile = gx >> 1;
    const int h0   = hy * 2;
    const int w0   = wtile * 64;
    const int r    = wv >> 1;
    const int ocbase = octile * 128 + (wv & 1) * 64;
    const int ocf0   = octile * 8 + (wv & 1) * 4;

    // B-read base addrs: ps = 16p + c + kx; XOR term p-independent
    int addrB[3];
    #pragma unroll
    for (int kx = 0; kx < 3; ++kx) {
        int ps0 = c + kx;
        addrB[kx] = r * 4224 + ps0 * 64 + ((g ^ ((ps0 >> 1) & 3)) << 4);
    }

    // staging source offsets (chunk-invariant)
    int so[5];
    #pragma unroll
    for (int it = 0; it < 5; ++it) {
        int u   = it * 256 + tid;
        int row = u / 264;
        int rem = u - row * 264;
        int ps  = rem >> 2;
        int s   = rem & 3;
        int icq = s ^ ((ps >> 1) & 3);
        so[it] = ((n * 130 + h0 + row) * 130 + (w0 + ps)) * CIN + icq * 8;
    }

    auto STAGE = [&](int chunk, int bsel) {
        const unsigned short* bp = in + chunk * 32;
        char* lb = (char*)lds + bsel * 17408 + tid * 16;
        #pragma unroll
        for (int it = 0; it < 4; ++it)
            GL_LDS(bp + so[it], lb + it * 4096);
        if (wv == 0)
            GL_LDS(bp + so[4], lb + 16384);
    };

    f32x4 acc[4][4];
    #pragma unroll
    for (int m = 0; m < 4; ++m)
        #pragma unroll
        for (int p = 0; p < 4; ++p) acc[m][p] = 0.0f;

    const int NC = CIN / 32;
    STAGE(0, 0);
    __syncthreads();

    for (int chunk = 0; chunk < NC; ++chunk) {
        const int cur = chunk & 1;
        if (chunk + 1 < NC) STAGE(chunk + 1, cur ^ 1);  // prefetch overlaps MFMA
        const char* lb = (const char*)lds + cur * 17408;
        #pragma unroll
        for (int kk = 0; kk < 9; ++kk) {
            const int ky = kk / 3, kx = kk % 3;
            s16x8 af[4], bf[4];
            #pragma unroll
            for (int m = 0; m < 4; ++m)
                af[m] = *(const s16x8*)(wpk
                    + ((size_t)((chunk * 9 + kk) * (COUT / 16) + ocf0 + m)) * 512 + lane * 8);
            #pragma unroll
            for (int p = 0; p < 4; ++p)
                bf[p] = *(const s16x8*)(lb + addrB[kx] + ky * 4224 + p * 1024);
            #pragma unroll
            for (int m = 0; m < 4; ++m)
                #pragma unroll
                for (int p = 0; p < 4; ++p)
                    acc[m][p] = __builtin_amdgcn_mfma_f32_16x16x32_bf16(af[m], bf[p], acc[m][p], 0, 0, 0);
        }
        __syncthreads();
    }

    // epilogue: wave (r, ochalf) writes row h0+r, cols w0..w0+63
    #pragma unroll
    for (int m = 0; m < 4; ++m) {
        const int oc4 = ocbase + m * 16 + g * 4;
        const f4v s4 = *(const f4v*)(sc + oc4);
        const f4v b4 = *(const f4v*)(bi + oc4);
        #pragma unroll
        for (int p = 0; p < 4; ++p) {
            const int w = w0 + p * 16 + c;
            float y[4];
            #pragma unroll
            for (int j = 0; j < 4; ++j) {
                y[j] = acc[m][p][j] * s4[j] + b4[j];
                if (RELU) y[j] = fmaxf(y[j], 0.0f);
            }
            if (OUTF32) {
                float* op = (float*)outv + (((size_t)n * COUT + oc4) << 14) + ((h0 + r) << 7) + w;
                op[0] = y[0]; op[16384] = y[1]; op[32768] = y[2]; op[49152] = y[3];
            } else {
                u16x4 pk;
                #pragma unroll
                for (int j = 0; j < 4; ++j) pk[j] = f2bf(y[j]);
                *(u16x4*)((unsigned short*)outv
                    + ((size_t)(n * 130 + h0 + r + 1) * 130 + w + 1) * COUT + oc4) = pk;
            }
        }
    }
}

// ---------------------------------------------------------------------------
// conv1x1 + BN affine fused residual add + ReLU, in-place on io (bf16 NHWC pad).
// ---------------------------------------------------------------------------
__global__ __launch_bounds__(256, 2)
void conv1_mfma(const unsigned short* __restrict__ xb,
                const unsigned short* __restrict__ w1pk,
                const float* __restrict__ sc, const float* __restrict__ bi,
                unsigned short* __restrict__ io)
{
    const int tid  = threadIdx.x;
    const int h    = blockIdx.y;
    const int n    = blockIdx.z;
    const int lane = tid & 63;
    const int wv   = tid >> 6;
    const int c    = lane & 15;
    const int g    = lane >> 4;
    const int pixbase = (wv >> 1) * 64;
    const int ocbase  = blockIdx.x * 128 + (wv & 1) * 64;
    const int ocf0    = blockIdx.x * 8 + (wv & 1) * 4;
    const size_t pixrow = ((size_t)(n * 130 + h + 1) * 130 + (pixbase + c + 1)) * 256;

    f32x4 acc[4][4];
    #pragma unroll
    for (int m = 0; m < 4; ++m)
        #pragma unroll
        for (int p = 0; p < 4; ++p) acc[m][p] = 0.0f;

    s16x8 a0[4], b0[4], a1[4], b1[4];

#define LOADC(ck, A, B) do {                                                        \
    _Pragma("unroll") for (int p = 0; p < 4; ++p)                                   \
        B[p] = *(const s16x8*)(xb + pixrow + (size_t)(16 * p) * 256 + (ck) * 32 + g * 8); \
    _Pragma("unroll") for (int m = 0; m < 4; ++m)                                   \
        A[m] = *(const s16x8*)(w1pk + ((size_t)((ck) * 16 + ocf0 + m)) * 512 + lane * 8); \
} while (0)
#define MM(A, B)                                                                    \
    _Pragma("unroll") for (int m = 0; m < 4; ++m)                                   \
        _Pragma("unroll") for (int p = 0; p < 4; ++p)                               \
            acc[m][p] = __builtin_amdgcn_mfma_f32_16x16x32_bf16(A[m], B[p], acc[m][p], 0, 0, 0)

    LOADC(0, a0, b0);
    #pragma unroll
    for (int ck = 0; ck < 8; ++ck) {
        if ((ck & 1) == 0) { if (ck < 7) LOADC(ck + 1, a1, b1); MM(a0, b0); }
        else               { if (ck < 7) LOADC(ck + 1, a0, b0); MM(a1, b1); }
    }
#undef LOADC
#undef MM

    #pragma unroll
    for (int m = 0; m < 4; ++m) {
        const int oc4 = ocbase + m * 16 + g * 4;
        const f4v s4 = *(const f4v*)(sc + oc4);
        const f4v b4 = *(const f4v*)(bi + oc4);
        #pragma unroll
        for (int p = 0; p < 4; ++p) {
            const int pix = pixbase + p * 16 + c;
            size_t idx = ((size_t)(n * 130 + h + 1) * 130 + pix + 1) * 256 + oc4;
            u16x4 old = *(const u16x4*)(io + idx);
            u16x4 pk;
            #pragma unroll
            for (int j = 0; j < 4; ++j) {
                float y = acc[m][p][j] * s4[j] + b4[j] + bf2f(old[j]);
                pk[j] = f2bf(fmaxf(y, 0.0f));
            }
            *(u16x4*)(io + idx) = pk;
        }
    }
}

// ---------------------------------------------------------------------------
// fused H-pools, 8-deep load batching:
//   even blocks: ta = revcummaxH(ta)   (top pool)
//   odd  blocks: tb = cummaxH(tb)      (bottom pool)
// grid 2048 = 2 * (n*128 + w), block 128 (thread = channel)
// ---------------------------------------------------------------------------
__global__ __launch_bounds__(128)
void pool_h2_k(unsigned short* __restrict__ ta, unsigned short* __restrict__ tb)
{
    const int sel = blockIdx.x & 1;
    const int col = blockIdx.x >> 1;
    unsigned short* p = sel ? tb : ta;
    const int n = col >> 7, w = col & 127, cth = threadIdx.x;
    unsigned short* base = p + (((size_t)n * 130 + 1) * 130 + (w + 1)) * 128 + cth;
    const int stride = 130 * 128;
    float m = -3.402823466e+38f;
    if (sel == 0) {
        for (int gq = 0; gq < 16; ++gq) {
            const int h0 = 127 - gq * 8;
            float v[8];
            #pragma unroll
            for (int j = 0; j < 8; ++j) v[j] = bf2f(base[(size_t)(h0 - j) * stride]);
            unsigned short o[8];
            #pragma unroll
            for (int j = 0; j < 8; ++j) { m = fmaxf(m, v[j]); o[j] = f2bf(m); }
            #pragma unroll
            for (int j = 0; j < 8; ++j) base[(size_t)(h0 - j) * stride] = o[j];
        }
    } else {
        for (int gq = 0; gq < 16; ++gq) {
            const int h0 = gq * 8;
            float v[8];
            #pragma unroll
            for (int j = 0; j < 8; ++j) v[j] = bf2f(base[(size_t)(h0 + j) * stride]);
            unsigned short o[8];
            #pragma unroll
            for (int j = 0; j < 8; ++j) { m = fmaxf(m, v[j]); o[j] = f2bf(m); }
            #pragma unroll
            for (int j = 0; j < 8; ++j) base[(size_t)(h0 + j) * stride] = o[j];
        }
    }
}

// ---------------------------------------------------------------------------
// fused W-pools + add, 8-deep load batching:
//   even blocks: ta += revcummaxW(la)   (left pool into u1)
//   odd  blocks: tb += cummaxW(lb)      (right pool into u2)
// grid 2048 = 2 * (n*128 + h), block 128 (thread = channel)
// ---------------------------------------------------------------------------
__global__ __launch_bounds__(128)
void pool_w_add2_k(const unsigned short* __restrict__ la, unsigned short* __restrict__ ta,
                   const unsigned short* __restrict__ lb, unsigned short* __restrict__ tb)
{
    const int sel = blockIdx.x & 1;
    const int row = blockIdx.x >> 1;
    const unsigned short* ls = sel ? lb : la;
    unsigned short* td = sel ? tb : ta;
    const int n = row >> 7, hh = row & 127, cth = threadIdx.x;
    const size_t rowbase = ((size_t)(n * 130 + hh + 1) * 130) * 128 + cth;
    float m = -3.402823466e+38f;
    if (sel == 0) {
        for (int gq = 0; gq < 16; ++gq) {
            const int w0 = 127 - gq * 8;
            float lv[8], tv[8];
            #pragma unroll
            for (int j = 0; j < 8; ++j) {
                size_t off = rowbase + (size_t)(w0 - j + 1) * 128;
                lv[j] = bf2f(ls[off]); tv[j] = bf2f(td[off]);
            }
            unsigned short o[8];
            #pragma unroll
            for (int j = 0; j < 8; ++j) { m = fmaxf(m, lv[j]); o[j] = f2bf(m + tv[j]); }
            #pragma unroll
            for (int j = 0; j < 8; ++j) td[rowbase + (size_t)(w0 - j + 1) * 128] = o[j];
        }
    } else {
        for (int gq = 0; gq < 16; ++gq) {
            const int w0 = gq * 8;
            float lv[8], tv[8];
            #pragma unroll
            for (int j = 0; j < 8; ++j) {
                size_t off = rowbase + (size_t)(w0 + j + 1) * 128;
                lv[j] = bf2f(ls[off]); tv[j] = bf2f(td[off]);
            }
            unsigned short o[8];
            #pragma unroll
            for (int j = 0; j < 8; ++j) { m = fmaxf(m, lv[j]); o[j] = f2bf(m + tv[j]); }
            #pragma unroll
            for (int j = 0; j < 8; ++j) td[rowbase + (size_t)(w0 + j + 1) * 128] = o[j];
        }
    }
}

// ---------------------------------------------------------------------------
__global__ __launch_bounds__(256)
void padzero_k(unsigned short* __restrict__ t, int C)
{
    int idx = blockIdx.x * 256 + threadIdx.x;
    int n = blockIdx.y;
    int cpu = C >> 3;
    if (idx >= 516 * cpu) return;
    int cell = idx / cpu, cq = idx - cell * cpu;
    int h, w;
    if (cell < 260) { h = (cell < 130) ? -1 : 128; w = (cell % 130) - 1; }
    else { int j = cell - 260; w = (j < 128) ? -1 : 128; h = j & 127; }
    size_t off = (((size_t)n * 130 + h + 1) * 130 + (w + 1)) * C + cq * 8;
    uint4 z; z.x = 0; z.y = 0; z.z = 0; z.w = 0;
    *(uint4*)(t + off) = z;
}

// ---------------------------------------------------------------------------
__global__ __launch_bounds__(256)
void transform_x_k(const float* __restrict__ x, unsigned short* __restrict__ xb)
{
    __shared__ float sm[64][132];
    const int h = blockIdx.x, n = blockIdx.y, t = threadIdx.x;
    for (int cc0 = 0; cc0 < 256; cc0 += 64) {
        __syncthreads();
        {
            int ci = t >> 7, wi = t & 127;
            #pragma unroll 8
            for (int k = 0; k < 32; ++k)
                sm[ci + 2 * k][wi] = x[((size_t)(n * 256 + cc0 + ci + 2 * k) << 14) + (h << 7) + wi];
        }
        __syncthreads();
        {
            int wi = t >> 1, cq = t & 1;
            unsigned short tmp[32];
            #pragma unroll
            for (int m2 = 0; m2 < 32; ++m2) tmp[m2] = f2bf(sm[cq * 32 + m2][wi]);
            unsigned short* dst = xb + (((size_t)n * 130 + h + 1) * 130 + wi + 1) * 256 + cc0 + cq * 32;
            #pragma unroll
            for (int q = 0; q < 4; ++q) *(uint4*)(dst + q * 8) = *(const uint4*)(tmp + q * 8);
        }
    }
}

// ---------------------------------------------------------------------------
__global__ __launch_bounds__(256)
void prepack3_k(const float* __restrict__ w, unsigned short* __restrict__ dst,
                int CIN, int COUT)
{
    int idx = blockIdx.x * 256 + threadIdx.x;
    if (idx >= COUT * CIN * 9) return;
    int kk = idx % 9; int rest = idx / 9;
    int ic = rest % CIN; int oc = rest / CIN;
    float v = w[(size_t)(oc * CIN + ic) * 9 + kk];
    int chunk = ic >> 5, icr = ic & 31, gg = icr >> 3, j = icr & 7;
    int m = oc >> 4, ocr = oc & 15, ln = gg * 16 + ocr;
    size_t off = ((size_t)((chunk * 9 + kk) * (COUT / 16) + m)) * 512 + ln * 8 + j;
    dst[off] = f2bf(v);
}

__global__ __launch_bounds__(256)
void prepack1_k(const float* __restrict__ w, unsigned short* __restrict__ dst)
{
    int idx = blockIdx.x * 256 + threadIdx.x;
    if (idx >= 65536) return;
    int ic = idx & 255, oc = idx >> 8;
    float v = w[oc * 256 + ic];
    int chunk = ic >> 5, icr = ic & 31, gg = icr >> 3, j = icr & 7;
    int m = oc >> 4, ocr = oc & 15, ln = gg * 16 + ocr;
    size_t off = ((size_t)(chunk * 16 + m)) * 512 + ln * 8 + j;
    dst[off] = f2bf(v);
}

// ---------------------------------------------------------------------------
extern "C" void kernel_launch(void* const* d_in, const int* in_sizes, int n_in,
                              void* d_out, int out_size, void* d_ws, size_t ws_size,
                              hipStream_t stream)
{
    const float* x     = (const float*)d_in[0];
    const float* w_t   = (const float*)d_in[1];
    const float* s_t   = (const float*)d_in[2];
    const float* b_t   = (const float*)d_in[3];
    const float* w_l   = (const float*)d_in[4];
    const float* s_l   = (const float*)d_in[5];
    const float* b_l   = (const float*)d_in[6];
    const float* w_b   = (const float*)d_in[7];
    const float* s_b   = (const float*)d_in[8];
    const float* b_b   = (const float*)d_in[9];
    const float* w_r   = (const float*)d_in[10];
    const float* s_r   = (const float*)d_in[11];
    const float* b_r   = (const float*)d_in[12];
    const float* w_tl3 = (const float*)d_in[13];
    const float* s_tl3 = (const float*)d_in[14];
    const float* b_tl3 = (const float*)d_in[15];
    const float* w_br3 = (const float*)d_in[16];
    const float* s_br3 = (const float*)d_in[17];
    const float* b_br3 = (const float*)d_in[18];
    const float* w_tl1 = (const float*)d_in[19];
    const float* s_tl1 = (const float*)d_in[20];
    const float* b_tl1 = (const float*)d_in[21];
    const float* w_br1 = (const float*)d_in[22];
    const float* s_br1 = (const float*)d_in[23];
    const float* b_br1 = (const float*)d_in[24];
    const float* w_tlo = (const float*)d_in[25];
    const float* s_tlo = (const float*)d_in[26];
    const float* b_tlo = (const float*)d_in[27];
    const float* w_bro = (const float*)d_in[28];
    const float* s_bro = (const float*)d_in[29];
    const float* b_bro = (const float*)d_in[30];

    typedef unsigned short ush;
    const size_t T256 = (size_t)8 * 130 * 130 * 256;
    const size_t T128 = (size_t)8 * 130 * 130 * 128;

    ush* xb = (ush*)d_ws;
    ush* tt = xb + T256;
    ush* bb = tt + T128;
    ush* ll = bb + T128;
    ush* rr = ll + T128;
    ush* wq = rr + T128;
    ush* wp_t   = wq;
    ush* wp_l   = wp_t   + 294912;
    ush* wp_b   = wp_l   + 294912;
    ush* wp_r   = wp_b   + 294912;
    ush* wp_tl3 = wp_r   + 294912;
    ush* wp_br3 = wp_tl3 + 294912;
    ush* wp_tlo = wp_br3 + 294912;
    ush* wp_bro = wp_tlo + 589824;
    ush* wp_tl1 = wp_bro + 589824;
    ush* wp_br1 = wp_tl1 + 65536;
    ush* tl = ll;

    prepack3_k<<<dim3((294912 + 255) / 256), dim3(256), 0, stream>>>(w_t,   wp_t,   256, 128);
    prepack3_k<<<dim3((294912 + 255) / 256), dim3(256), 0, stream>>>(w_l,   wp_l,   256, 128);
    prepack3_k<<<dim3((294912 + 255) / 256), dim3(256), 0, stream>>>(w_b,   wp_b,   256, 128);
    prepack3_k<<<dim3((294912 + 255) / 256), dim3(256), 0, stream>>>(w_r,   wp_r,   256, 128);
    prepack3_k<<<dim3((294912 + 255) / 256), dim3(256), 0, stream>>>(w_tl3, wp_tl3, 128, 256);
    prepack3_k<<<dim3((294912 + 255) / 256), dim3(256), 0, stream>>>(w_br3, wp_br3, 128, 256);
    prepack3_k<<<dim3((589824 + 255) / 256), dim3(256), 0, stream>>>(w_tlo, wp_tlo, 256, 256);
    prepack3_k<<<dim3((589824 + 255) / 256), dim3(256), 0, stream>>>(w_bro, wp_bro, 256, 256);
    prepack1_k<<<dim3(256), dim3(256), 0, stream>>>(w_tl1, wp_tl1);
    prepack1_k<<<dim3(256), dim3(256), 0, stream>>>(w_br1, wp_br1);

    padzero_k<<<dim3(66, 8), dim3(256), 0, stream>>>(xb, 256);
    padzero_k<<<dim3(33, 8), dim3(256), 0, stream>>>(tt, 128);
    padzero_k<<<dim3(33, 8), dim3(256), 0, stream>>>(bb, 128);
    padzero_k<<<dim3(33, 8), dim3(256), 0, stream>>>(ll, 128);
    padzero_k<<<dim3(33, 8), dim3(256), 0, stream>>>(rr, 128);

    transform_x_k<<<dim3(128, 8), dim3(256), 0, stream>>>(x, xb);

    // stage A (m4p4 everywhere). A/B: t,l swizzled; b,r not.
    conv3_mfma<256, 128, true, false, true ><<<dim3(2, 64, 8), dim3(256), 0, stream>>>(xb, wp_t, s_t, b_t, tt);
    conv3_mfma<256, 128, true, false, true ><<<dim3(2, 64, 8), dim3(256), 0, stream>>>(xb, wp_l, s_l, b_l, ll);
    conv3_mfma<256, 128, true, false, false><<<dim3(2, 64, 8), dim3(256), 0, stream>>>(xb, wp_b, s_b, b_b, bb);
    conv3_mfma<256, 128, true, false, false><<<dim3(2, 64, 8), dim3(256), 0, stream>>>(xb, wp_r, s_r, b_r, rr);

    // pools fused: u1 = revcummaxH(tt)+revcummaxW(ll); u2 = cummaxH(bb)+cummaxW(rr)
    pool_h2_k<<<dim3(2048), dim3(128), 0, stream>>>(tt, bb);
    pool_w_add2_k<<<dim3(2048), dim3(128), 0, stream>>>(ll, tt, rr, bb);

    // tl chain (swizzled) / br chain (not) — free A/B on identical shapes
    padzero_k<<<dim3(66, 8), dim3(256), 0, stream>>>(tl, 256);
    conv3_mfma<128, 256, false, false, true ><<<dim3(4, 64, 8), dim3(256), 0, stream>>>(tt, wp_tl3, s_tl3, b_tl3, tl);
    conv1_mfma<<<dim3(2, 128, 8), dim3(256), 0, stream>>>(xb, wp_tl1, s_tl1, b_tl1, tl);
    conv3_mfma<256, 256, true, true, true ><<<dim3(4, 64, 8), dim3(256), 0, stream>>>(tl, wp_tlo, s_tlo, b_tlo, d_out);

    conv3_mfma<128, 256, false, false, false><<<dim3(4, 64, 8), dim3(256), 0, stream>>>(bb, wp_br3, s_br3, b_br3, tl);
    conv1_mfma<<<dim3(2, 128, 8), dim3(256), 0, stream>>>(xb, wp_br1, s_br1, b_br1, tl);
    conv3_mfma<256, 256, true, true, false><<<dim3(4, 64, 8), dim3(256), 0, stream>>>(tl, wp_bro, s_bro, b_bro,
                                                                                      (float*)d_out + 33554432);
}

// Round 8
// 924.802 us; speedup vs baseline: 1.3009x; 1.0840x over previous
//
#include <hip/hip_runtime.h>
#include <cstdint>
#include <cstddef>

// B=8, C=256/128, H=W=128. Padded NHWC bf16 tensors: [n][130][130][C], pad ring = 0.
// elem(n,h,w,c) = ((n*130 + h+1)*130 + (w+1))*C + c

typedef float  f32x4 __attribute__((ext_vector_type(4)));
typedef float  f4v   __attribute__((ext_vector_type(4)));
typedef short  s16x8 __attribute__((ext_vector_type(8)));
typedef unsigned short u16x4 __attribute__((ext_vector_type(4)));

__device__ __forceinline__ float bf2f(unsigned short u) {
    unsigned x = ((unsigned)u) << 16;
    return __builtin_bit_cast(float, x);
}
__device__ __forceinline__ unsigned short f2bf(float f) {
    unsigned u = __builtin_bit_cast(unsigned, f);
    unsigned r = (u + 0x7fffu + ((u >> 16) & 1u)) >> 16;
    return (unsigned short)r;
}

#define GL_LDS(gp, lp) __builtin_amdgcn_global_load_lds( \
    (const __attribute__((address_space(1))) unsigned int*)(const void*)(gp), \
    (__attribute__((address_space(3))) unsigned int*)(void*)(lp), 16, 0, 0)

// ---------------------------------------------------------------------------
// conv3x3 + BN (+opt ReLU), bf16 MFMA implicit GEMM. m4p4 geometry, 4 blk/CU,
// 2-phase dbuf pipeline (round-5 proven). Bijective XCD swizzle.
// grid ((COUT/128)*2, 64, 8)
// ---------------------------------------------------------------------------
template<int CIN, int COUT, bool RELU, bool OUTF32, bool SWZ>
__global__ __launch_bounds__(256, 4)
void conv3_mfma(const unsigned short* __restrict__ in,
                const unsigned short* __restrict__ wpk,
                const float* __restrict__ sc, const float* __restrict__ bi,
                void* __restrict__ outv)
{
    __shared__ unsigned short lds[2][8704];      // 2 x 17408 B
    const int tid  = threadIdx.x;
    const int lane = tid & 63;
    const int wv   = tid >> 6;
    const int c    = lane & 15;
    const int g    = lane >> 4;

    constexpr int GX  = (COUT / 128) * 2;
    int gx, hy, n;
    if (SWZ) {
        constexpr int NWG = GX * 64 * 8;
        constexpr int Q   = NWG / 8;
        const int braw = blockIdx.x + GX * (blockIdx.y + 64 * blockIdx.z);
        const int wl   = (braw & 7) * Q + (braw >> 3);
        gx = wl % GX;
        const int rest = wl / GX;
        hy = rest & 63;
        n  = rest >> 6;
    } else {
        gx = blockIdx.x; hy = blockIdx.y; n = blockIdx.z;
    }
    const int wtile  = gx & 1;
    const int octile = gx >> 1;
    const int h0   = hy * 2;
    const int w0   = wtile * 64;
    const int r    = wv >> 1;
    const int ocbase = octile * 128 + (wv & 1) * 64;
    const int ocf0   = octile * 8 + (wv & 1) * 4;

    int addrB[3];
    #pragma unroll
    for (int kx = 0; kx < 3; ++kx) {
        int ps0 = c + kx;
        addrB[kx] = r * 4224 + ps0 * 64 + ((g ^ ((ps0 >> 1) & 3)) << 4);
    }

    int so[5];
    #pragma unroll
    for (int it = 0; it < 5; ++it) {
        int u   = it * 256 + tid;
        int row = u / 264;
        int rem = u - row * 264;
        int ps  = rem >> 2;
        int s   = rem & 3;
        int icq = s ^ ((ps >> 1) & 3);
        so[it] = ((n * 130 + h0 + row) * 130 + (w0 + ps)) * CIN + icq * 8;
    }

    auto STAGE = [&](int chunk, int bsel) {
        const unsigned short* bp = in + chunk * 32;
        char* lb = (char*)lds + bsel * 17408 + tid * 16;
        #pragma unroll
        for (int it = 0; it < 4; ++it)
            GL_LDS(bp + so[it], lb + it * 4096);
        if (wv == 0)
            GL_LDS(bp + so[4], lb + 16384);
    };

    f32x4 acc[4][4];
    #pragma unroll
    for (int m = 0; m < 4; ++m)
        #pragma unroll
        for (int p = 0; p < 4; ++p) acc[m][p] = 0.0f;

    const int NC = CIN / 32;
    STAGE(0, 0);
    __syncthreads();

    for (int chunk = 0; chunk < NC; ++chunk) {
        const int cur = chunk & 1;
        if (chunk + 1 < NC) STAGE(chunk + 1, cur ^ 1);
        const char* lb = (const char*)lds + cur * 17408;
        #pragma unroll
        for (int kk = 0; kk < 9; ++kk) {
            const int ky = kk / 3, kx = kk % 3;
            s16x8 af[4], bf[4];
            #pragma unroll
            for (int m = 0; m < 4; ++m)
                af[m] = *(const s16x8*)(wpk
                    + ((size_t)((chunk * 9 + kk) * (COUT / 16) + ocf0 + m)) * 512 + lane * 8);
            #pragma unroll
            for (int p = 0; p < 4; ++p)
                bf[p] = *(const s16x8*)(lb + addrB[kx] + ky * 4224 + p * 1024);
            #pragma unroll
            for (int m = 0; m < 4; ++m)
                #pragma unroll
                for (int p = 0; p < 4; ++p)
                    acc[m][p] = __builtin_amdgcn_mfma_f32_16x16x32_bf16(af[m], bf[p], acc[m][p], 0, 0, 0);
        }
        __syncthreads();
    }

    #pragma unroll
    for (int m = 0; m < 4; ++m) {
        const int oc4 = ocbase + m * 16 + g * 4;
        const f4v s4 = *(const f4v*)(sc + oc4);
        const f4v b4 = *(const f4v*)(bi + oc4);
        #pragma unroll
        for (int p = 0; p < 4; ++p) {
            const int w = w0 + p * 16 + c;
            float y[4];
            #pragma unroll
            for (int j = 0; j < 4; ++j) {
                y[j] = acc[m][p][j] * s4[j] + b4[j];
                if (RELU) y[j] = fmaxf(y[j], 0.0f);
            }
            if (OUTF32) {
                float* op = (float*)outv + (((size_t)n * COUT + oc4) << 14) + ((h0 + r) << 7) + w;
                op[0] = y[0]; op[16384] = y[1]; op[32768] = y[2]; op[49152] = y[3];
            } else {
                u16x4 pk;
                #pragma unroll
                for (int j = 0; j < 4; ++j) pk[j] = f2bf(y[j]);
                *(u16x4*)((unsigned short*)outv
                    + ((size_t)(n * 130 + h0 + r + 1) * 130 + w + 1) * COUT + oc4) = pk;
            }
        }
    }
}

// ---------------------------------------------------------------------------
// MERGED stage-A: t,l,b,r (CIN=256 -> 128 each) in ONE dispatch.
// Custom XCD map: b&7 = XCD; within an XCD the 4 q-variants of one spatial
// tile run back-to-back -> xb tile enters that XCD's L2 once.
// q: 0=t,1=l,2=b,3=r. wq = wp_t + q*294912; s/b from concat sA/bA (q*128).
// out tensor: tt + outoff(q)*T128, outoff = {0:tt,1:ll(2),2:bb(1),3:rr(3)}.
// grid (4096,1,1)
// ---------------------------------------------------------------------------
__global__ __launch_bounds__(256, 4)
void conv3_tlbr(const unsigned short* __restrict__ in,
                const unsigned short* __restrict__ wq0,
                const float* __restrict__ sA, const float* __restrict__ bA,
                unsigned short* __restrict__ tt0)
{
    __shared__ unsigned short lds[2][8704];
    const int tid  = threadIdx.x;
    const int lane = tid & 63;
    const int wv   = tid >> 6;
    const int c    = lane & 15;
    const int g    = lane >> 4;

    const int b  = blockIdx.x;
    const int x  = b & 7;            // XCD slot
    const int t  = b >> 3;
    const int q  = t & 3;            // conv id, fastest within XCD sequence
    const int ts = x + 8 * (t >> 2); // spatial/batch tile 0..1023
    const int wtile = ts & 1;
    const int hy    = (ts >> 1) & 63;
    const int n     = ts >> 7;
    const int h0 = hy * 2;
    const int w0 = wtile * 64;
    const int r  = wv >> 1;
    const int ocbase = (wv & 1) * 64;
    const int ocf0   = (wv & 1) * 4;

    const unsigned short* wpk = wq0 + q * 294912;
    const int outoff = ((q & 1) << 1) | (q >> 1);          // 0,2,1,3
    unsigned short* outv = tt0 + (size_t)outoff * ((size_t)8 * 130 * 130 * 128);
    const float* sc = sA + q * 128;
    const float* bi = bA + q * 128;

    int addrB[3];
    #pragma unroll
    for (int kx = 0; kx < 3; ++kx) {
        int ps0 = c + kx;
        addrB[kx] = r * 4224 + ps0 * 64 + ((g ^ ((ps0 >> 1) & 3)) << 4);
    }

    int so[5];
    #pragma unroll
    for (int it = 0; it < 5; ++it) {
        int u   = it * 256 + tid;
        int row = u / 264;
        int rem = u - row * 264;
        int ps  = rem >> 2;
        int s   = rem & 3;
        int icq = s ^ ((ps >> 1) & 3);
        so[it] = ((n * 130 + h0 + row) * 130 + (w0 + ps)) * 256 + icq * 8;
    }

    auto STAGE = [&](int chunk, int bsel) {
        const unsigned short* bp = in + chunk * 32;
        char* lb = (char*)lds + bsel * 17408 + tid * 16;
        #pragma unroll
        for (int it = 0; it < 4; ++it)
            GL_LDS(bp + so[it], lb + it * 4096);
        if (wv == 0)
            GL_LDS(bp + so[4], lb + 16384);
    };

    f32x4 acc[4][4];
    #pragma unroll
    for (int m = 0; m < 4; ++m)
        #pragma unroll
        for (int p = 0; p < 4; ++p) acc[m][p] = 0.0f;

    STAGE(0, 0);
    __syncthreads();

    for (int chunk = 0; chunk < 8; ++chunk) {
        const int cur = chunk & 1;
        if (chunk + 1 < 8) STAGE(chunk + 1, cur ^ 1);
        const char* lb = (const char*)lds + cur * 17408;
        #pragma unroll
        for (int kk = 0; kk < 9; ++kk) {
            const int ky = kk / 3, kx = kk % 3;
            s16x8 af[4], bf[4];
            #pragma unroll
            for (int m = 0; m < 4; ++m)
                af[m] = *(const s16x8*)(wpk
                    + ((size_t)((chunk * 9 + kk) * 8 + ocf0 + m)) * 512 + lane * 8);
            #pragma unroll
            for (int p = 0; p < 4; ++p)
                bf[p] = *(const s16x8*)(lb + addrB[kx] + ky * 4224 + p * 1024);
            #pragma unroll
            for (int m = 0; m < 4; ++m)
                #pragma unroll
                for (int p = 0; p < 4; ++p)
                    acc[m][p] = __builtin_amdgcn_mfma_f32_16x16x32_bf16(af[m], bf[p], acc[m][p], 0, 0, 0);
        }
        __syncthreads();
    }

    #pragma unroll
    for (int m = 0; m < 4; ++m) {
        const int oc4 = ocbase + m * 16 + g * 4;
        const f4v s4 = *(const f4v*)(sc + oc4);
        const f4v b4 = *(const f4v*)(bi + oc4);
        #pragma unroll
        for (int p = 0; p < 4; ++p) {
            const int w = w0 + p * 16 + c;
            u16x4 pk;
            #pragma unroll
            for (int j = 0; j < 4; ++j)
                pk[j] = f2bf(fmaxf(acc[m][p][j] * s4[j] + b4[j], 0.0f));
            *(u16x4*)(outv + ((size_t)(n * 130 + h0 + r + 1) * 130 + w + 1) * 128 + oc4) = pk;
        }
    }
}

// ---------------------------------------------------------------------------
// conv1x1 + BN fused residual add + ReLU, in-place on io (bf16 NHWC pad).
// ---------------------------------------------------------------------------
__global__ __launch_bounds__(256, 2)
void conv1_mfma(const unsigned short* __restrict__ xb,
                const unsigned short* __restrict__ w1pk,
                const float* __restrict__ sc, const float* __restrict__ bi,
                unsigned short* __restrict__ io)
{
    const int tid  = threadIdx.x;
    const int h    = blockIdx.y;
    const int n    = blockIdx.z;
    const int lane = tid & 63;
    const int wv   = tid >> 6;
    const int c    = lane & 15;
    const int g    = lane >> 4;
    const int pixbase = (wv >> 1) * 64;
    const int ocbase  = blockIdx.x * 128 + (wv & 1) * 64;
    const int ocf0    = blockIdx.x * 8 + (wv & 1) * 4;
    const size_t pixrow = ((size_t)(n * 130 + h + 1) * 130 + (pixbase + c + 1)) * 256;

    f32x4 acc[4][4];
    #pragma unroll
    for (int m = 0; m < 4; ++m)
        #pragma unroll
        for (int p = 0; p < 4; ++p) acc[m][p] = 0.0f;

    s16x8 a0[4], b0[4], a1[4], b1[4];

#define LOADC(ck, A, B) do {                                                        \
    _Pragma("unroll") for (int p = 0; p < 4; ++p)                                   \
        B[p] = *(const s16x8*)(xb + pixrow + (size_t)(16 * p) * 256 + (ck) * 32 + g * 8); \
    _Pragma("unroll") for (int m = 0; m < 4; ++m)                                   \
        A[m] = *(const s16x8*)(w1pk + ((size_t)((ck) * 16 + ocf0 + m)) * 512 + lane * 8); \
} while (0)
#define MM(A, B)                                                                    \
    _Pragma("unroll") for (int m = 0; m < 4; ++m)                                   \
        _Pragma("unroll") for (int p = 0; p < 4; ++p)                               \
            acc[m][p] = __builtin_amdgcn_mfma_f32_16x16x32_bf16(A[m], B[p], acc[m][p], 0, 0, 0)

    LOADC(0, a0, b0);
    #pragma unroll
    for (int ck = 0; ck < 8; ++ck) {
        if ((ck & 1) == 0) { if (ck < 7) LOADC(ck + 1, a1, b1); MM(a0, b0); }
        else               { if (ck < 7) LOADC(ck + 1, a0, b0); MM(a1, b1); }
    }
#undef LOADC
#undef MM

    #pragma unroll
    for (int m = 0; m < 4; ++m) {
        const int oc4 = ocbase + m * 16 + g * 4;
        const f4v s4 = *(const f4v*)(sc + oc4);
        const f4v b4 = *(const f4v*)(bi + oc4);
        #pragma unroll
        for (int p = 0; p < 4; ++p) {
            const int pix = pixbase + p * 16 + c;
            size_t idx = ((size_t)(n * 130 + h + 1) * 130 + pix + 1) * 256 + oc4;
            u16x4 old = *(const u16x4*)(io + idx);
            u16x4 pk;
            #pragma unroll
            for (int j = 0; j < 4; ++j) {
                float y = acc[m][p][j] * s4[j] + b4[j] + bf2f(old[j]);
                pk[j] = f2bf(fmaxf(y, 0.0f));
            }
            *(u16x4*)(io + idx) = pk;
        }
    }
}

// ---------------------------------------------------------------------------
// fused H-pools (8-deep batching): even blk: ta=revcummaxH; odd: tb=cummaxH
// ---------------------------------------------------------------------------
__global__ __launch_bounds__(128)
void pool_h2_k(unsigned short* __restrict__ ta, unsigned short* __restrict__ tb)
{
    const int sel = blockIdx.x & 1;
    const int col = blockIdx.x >> 1;
    unsigned short* p = sel ? tb : ta;
    const int n = col >> 7, w = col & 127, cth = threadIdx.x;
    unsigned short* base = p + (((size_t)n * 130 + 1) * 130 + (w + 1)) * 128 + cth;
    const int stride = 130 * 128;
    float m = -3.402823466e+38f;
    if (sel == 0) {
        for (int gq = 0; gq < 16; ++gq) {
            const int h0 = 127 - gq * 8;
            float v[8];
            #pragma unroll
            for (int j = 0; j < 8; ++j) v[j] = bf2f(base[(size_t)(h0 - j) * stride]);
            unsigned short o[8];
            #pragma unroll
            for (int j = 0; j < 8; ++j) { m = fmaxf(m, v[j]); o[j] = f2bf(m); }
            #pragma unroll
            for (int j = 0; j < 8; ++j) base[(size_t)(h0 - j) * stride] = o[j];
        }
    } else {
        for (int gq = 0; gq < 16; ++gq) {
            const int h0 = gq * 8;
            float v[8];
            #pragma unroll
            for (int j = 0; j < 8; ++j) v[j] = bf2f(base[(size_t)(h0 + j) * stride]);
            unsigned short o[8];
            #pragma unroll
            for (int j = 0; j < 8; ++j) { m = fmaxf(m, v[j]); o[j] = f2bf(m); }
            #pragma unroll
            for (int j = 0; j < 8; ++j) base[(size_t)(h0 + j) * stride] = o[j];
        }
    }
}

// ---------------------------------------------------------------------------
// fused W-pools + add: even blk: ta += revcummaxW(la); odd: tb += cummaxW(lb)
// ---------------------------------------------------------------------------
__global__ __launch_bounds__(128)
void pool_w_add2_k(const unsigned short* __restrict__ la, unsigned short* __restrict__ ta,
                   const unsigned short* __restrict__ lb, unsigned short* __restrict__ tb)
{
    const int sel = blockIdx.x & 1;
    const int row = blockIdx.x >> 1;
    const unsigned short* ls = sel ? lb : la;
    unsigned short* td = sel ? tb : ta;
    const int n = row >> 7, hh = row & 127, cth = threadIdx.x;
    const size_t rowbase = ((size_t)(n * 130 + hh + 1) * 130) * 128 + cth;
    float m = -3.402823466e+38f;
    if (sel == 0) {
        for (int gq = 0; gq < 16; ++gq) {
            const int w0 = 127 - gq * 8;
            float lv[8], tv[8];
            #pragma unroll
            for (int j = 0; j < 8; ++j) {
                size_t off = rowbase + (size_t)(w0 - j + 1) * 128;
                lv[j] = bf2f(ls[off]); tv[j] = bf2f(td[off]);
            }
            unsigned short o[8];
            #pragma unroll
            for (int j = 0; j < 8; ++j) { m = fmaxf(m, lv[j]); o[j] = f2bf(m + tv[j]); }
            #pragma unroll
            for (int j = 0; j < 8; ++j) td[rowbase + (size_t)(w0 - j + 1) * 128] = o[j];
        }
    } else {
        for (int gq = 0; gq < 16; ++gq) {
            const int w0 = gq * 8;
            float lv[8], tv[8];
            #pragma unroll
            for (int j = 0; j < 8; ++j) {
                size_t off = rowbase + (size_t)(w0 + j + 1) * 128;
                lv[j] = bf2f(ls[off]); tv[j] = bf2f(td[off]);
            }
            unsigned short o[8];
            #pragma unroll
            for (int j = 0; j < 8; ++j) { m = fmaxf(m, lv[j]); o[j] = f2bf(m + tv[j]); }
            #pragma unroll
            for (int j = 0; j < 8; ++j) td[rowbase + (size_t)(w0 + j + 1) * 128] = o[j];
        }
    }
}

// ---------------------------------------------------------------------------
// pad-ring zero, single tensor (used for tl re-pad after pools)
// ---------------------------------------------------------------------------
__global__ __launch_bounds__(256)
void padzero_k(unsigned short* __restrict__ t, int C)
{
    int idx = blockIdx.x * 256 + threadIdx.x;
    int n = blockIdx.y;
    int cpu = C >> 3;
    if (idx >= 516 * cpu) return;
    int cell = idx / cpu, cq = idx - cell * cpu;
    int h, w;
    if (cell < 260) { h = (cell < 130) ? -1 : 128; w = (cell % 130) - 1; }
    else { int j = cell - 260; w = (j < 128) ? -1 : 128; h = j & 127; }
    size_t off = (((size_t)n * 130 + h + 1) * 130 + (w + 1)) * C + cq * 8;
    uint4 z; z.x = 0; z.y = 0; z.z = 0; z.w = 0;
    *(uint4*)(t + off) = z;
}

// ---------------------------------------------------------------------------
// merged pad-ring zero for 5 tensors. grid (516, 5, 8): y = tensor id.
// ---------------------------------------------------------------------------
__global__ __launch_bounds__(256)
void padzero_all_k(unsigned short* xb, unsigned short* tt, unsigned short* bb,
                   unsigned short* ll, unsigned short* rr)
{
    const int id = blockIdx.y;
    unsigned short* t = id == 0 ? xb : (id == 1 ? tt : (id == 2 ? bb : (id == 3 ? ll : rr)));
    const int C = id == 0 ? 256 : 128;
    int idx = blockIdx.x * 256 + threadIdx.x;
    int n = blockIdx.z;
    int cpu = C >> 3;
    if (idx >= 516 * cpu) return;
    int cell = idx / cpu, cq = idx - cell * cpu;
    int h, w;
    if (cell < 260) { h = (cell < 130) ? -1 : 128; w = (cell % 130) - 1; }
    else { int j = cell - 260; w = (j < 128) ? -1 : 128; h = j & 127; }
    size_t off = (((size_t)n * 130 + h + 1) * 130 + (w + 1)) * C + cq * 8;
    uint4 z; z.x = 0; z.y = 0; z.z = 0; z.w = 0;
    *(uint4*)(t + off) = z;
}

// ---------------------------------------------------------------------------
// x fp32 NCHW -> bf16 NHWC padded interior. grid (128 h, 8 n)
// ---------------------------------------------------------------------------
__global__ __launch_bounds__(256)
void transform_x_k(const float* __restrict__ x, unsigned short* __restrict__ xb)
{
    __shared__ float sm[64][132];
    const int h = blockIdx.x, n = blockIdx.y, t = threadIdx.x;
    for (int cc0 = 0; cc0 < 256; cc0 += 64) {
        __syncthreads();
        {
            int ci = t >> 7, wi = t & 127;
            #pragma unroll 8
            for (int k = 0; k < 32; ++k)
                sm[ci + 2 * k][wi] = x[((size_t)(n * 256 + cc0 + ci + 2 * k) << 14) + (h << 7) + wi];
        }
        __syncthreads();
        {
            int wi = t >> 1, cq = t & 1;
            unsigned short tmp[32];
            #pragma unroll
            for (int m2 = 0; m2 < 32; ++m2) tmp[m2] = f2bf(sm[cq * 32 + m2][wi]);
            unsigned short* dst = xb + (((size_t)n * 130 + h + 1) * 130 + wi + 1) * 256 + cc0 + cq * 32;
            #pragma unroll
            for (int q = 0; q < 4; ++q) *(uint4*)(dst + q * 8) = *(const uint4*)(tmp + q * 8);
        }
    }
}

// ---------------------------------------------------------------------------
// merged weight prepack: 8x conv3 + 2x conv1 + s/b concat for stage A.
// grid (2304, 11). y = job id. Frag map (as before):
//   frag = (chunk*9+kk)*(COUT/16) + oc>>4 ; lane = (icr>>3)*16 + (oc&15) ; j = icr&7
// ---------------------------------------------------------------------------
struct PrepArgs {
    const float* w[10];          // t,l,b,r,tl3,br3,tlo,bro,tl1,br1
    unsigned short* dst[10];
    const float* sv[4];          // s_t,s_l,s_b,s_r
    const float* bv[4];
    float* sA; float* bA;        // concat outputs [512]
};

__global__ __launch_bounds__(256)
void prepack_all_k(PrepArgs a)
{
    const int id = blockIdx.y;
    int idx = blockIdx.x * 256 + threadIdx.x;
    if (id == 10) {                       // s/b concat: 512 each
        if (idx < 512) {
            a.sA[idx] = a.sv[idx >> 7][idx & 127];
            a.bA[idx] = a.bv[idx >> 7][idx & 127];
        }
        return;
    }
    if (id >= 8) {                        // conv1 prepack (256x256)
        if (idx >= 65536) return;
        int ic = idx & 255, oc = idx >> 8;
        float v = a.w[id][oc * 256 + ic];
        int chunk = ic >> 5, icr = ic & 31, gg = icr >> 3, j = icr & 7;
        int m = oc >> 4, ocr = oc & 15, ln = gg * 16 + ocr;
        a.dst[id][((size_t)(chunk * 16 + m)) * 512 + ln * 8 + j] = f2bf(v);
        return;
    }
    const int CIN  = (id < 4) ? 256 : ((id < 6) ? 128 : 256);
    const int COUT = (id < 4) ? 128 : 256;
    if (idx >= COUT * CIN * 9) return;
    int kk = idx % 9; int rest = idx / 9;
    int ic = rest % CIN; int oc = rest / CIN;
    float v = a.w[id][(size_t)(oc * CIN + ic) * 9 + kk];
    int chunk = ic >> 5, icr = ic & 31, gg = icr >> 3, j = icr & 7;
    int m = oc >> 4, ocr = oc & 15, ln = gg * 16 + ocr;
    a.dst[id][((size_t)((chunk * 9 + kk) * (COUT / 16) + m)) * 512 + ln * 8 + j] = f2bf(v);
}

// ---------------------------------------------------------------------------
extern "C" void kernel_launch(void* const* d_in, const int* in_sizes, int n_in,
                              void* d_out, int out_size, void* d_ws, size_t ws_size,
                              hipStream_t stream)
{
    const float* x     = (const float*)d_in[0];
    const float* w_t   = (const float*)d_in[1];
    const float* s_t   = (const float*)d_in[2];
    const float* b_t   = (const float*)d_in[3];
    const float* w_l   = (const float*)d_in[4];
    const float* s_l   = (const float*)d_in[5];
    const float* b_l   = (const float*)d_in[6];
    const float* w_b   = (const float*)d_in[7];
    const float* s_b   = (const float*)d_in[8];
    const float* b_b   = (const float*)d_in[9];
    const float* w_r   = (const float*)d_in[10];
    const float* s_r   = (const float*)d_in[11];
    const float* b_r   = (const float*)d_in[12];
    const float* w_tl3 = (const float*)d_in[13];
    const float* s_tl3 = (const float*)d_in[14];
    const float* b_tl3 = (const float*)d_in[15];
    const float* w_br3 = (const float*)d_in[16];
    const float* s_br3 = (const float*)d_in[17];
    const float* b_br3 = (const float*)d_in[18];
    const float* w_tl1 = (const float*)d_in[19];
    const float* s_tl1 = (const float*)d_in[20];
    const float* b_tl1 = (const float*)d_in[21];
    const float* w_br1 = (const float*)d_in[22];
    const float* s_br1 = (const float*)d_in[23];
    const float* b_br1 = (const float*)d_in[24];
    const float* w_tlo = (const float*)d_in[25];
    const float* s_tlo = (const float*)d_in[26];
    const float* b_tlo = (const float*)d_in[27];
    const float* w_bro = (const float*)d_in[28];
    const float* s_bro = (const float*)d_in[29];
    const float* b_bro = (const float*)d_in[30];

    typedef unsigned short ush;
    const size_t T256 = (size_t)8 * 130 * 130 * 256;
    const size_t T128 = (size_t)8 * 130 * 130 * 128;

    ush* xb = (ush*)d_ws;
    ush* tt = xb + T256;
    ush* bb = tt + T128;
    ush* ll = bb + T128;
    ush* rr = ll + T128;
    ush* wq = rr + T128;
    ush* wp_t   = wq;                    // 4x 294912, contiguous (q-indexed)
    ush* wp_l   = wp_t   + 294912;
    ush* wp_b   = wp_l   + 294912;
    ush* wp_r   = wp_b   + 294912;
    ush* wp_tl3 = wp_r   + 294912;
    ush* wp_br3 = wp_tl3 + 294912;
    ush* wp_tlo = wp_br3 + 294912;
    ush* wp_bro = wp_tlo + 589824;
    ush* wp_tl1 = wp_bro + 589824;
    ush* wp_br1 = wp_tl1 + 65536;
    float* sA   = (float*)(wp_br1 + 65536);  // 512 f
    float* bA   = sA + 512;                  // 512 f
    ush* tl = ll;                            // 256-ch buffer over ll+rr

    // setup: 3 dispatches (prepack-all, padzero-all, transform)
    PrepArgs pa;
    pa.w[0] = w_t;  pa.w[1] = w_l;  pa.w[2] = w_b;  pa.w[3] = w_r;
    pa.w[4] = w_tl3; pa.w[5] = w_br3; pa.w[6] = w_tlo; pa.w[7] = w_bro;
    pa.w[8] = w_tl1; pa.w[9] = w_br1;
    pa.dst[0] = wp_t;  pa.dst[1] = wp_l;  pa.dst[2] = wp_b;  pa.dst[3] = wp_r;
    pa.dst[4] = wp_tl3; pa.dst[5] = wp_br3; pa.dst[6] = wp_tlo; pa.dst[7] = wp_bro;
    pa.dst[8] = wp_tl1; pa.dst[9] = wp_br1;
    pa.sv[0] = s_t; pa.sv[1] = s_l; pa.sv[2] = s_b; pa.sv[3] = s_r;
    pa.bv[0] = b_t; pa.bv[1] = b_l; pa.bv[2] = b_b; pa.bv[3] = b_r;
    pa.sA = sA; pa.bA = bA;
    prepack_all_k<<<dim3(2304, 11), dim3(256), 0, stream>>>(pa);
    padzero_all_k<<<dim3(516, 5, 8), dim3(256), 0, stream>>>(xb, tt, bb, ll, rr);
    transform_x_k<<<dim3(128, 8), dim3(256), 0, stream>>>(x, xb);

    // stage A: t,l,b,r merged — one dispatch, XCD-tile-grouped
    conv3_tlbr<<<dim3(4096), dim3(256), 0, stream>>>(xb, wp_t, sA, bA, tt);

    // pools: u1 = revcummaxH(tt)+revcummaxW(ll); u2 = cummaxH(bb)+cummaxW(rr)
    pool_h2_k<<<dim3(2048), dim3(128), 0, stream>>>(tt, bb);
    pool_w_add2_k<<<dim3(2048), dim3(128), 0, stream>>>(ll, tt, rr, bb);

    // tl chain (tl buffer overlays ll+rr, now dead)
    padzero_k<<<dim3(66, 8), dim3(256), 0, stream>>>(tl, 256);
    conv3_mfma<128, 256, false, false, true><<<dim3(4, 64, 8), dim3(256), 0, stream>>>(tt, wp_tl3, s_tl3, b_tl3, tl);
    conv1_mfma<<<dim3(2, 128, 8), dim3(256), 0, stream>>>(xb, wp_tl1, s_tl1, b_tl1, tl);
    conv3_mfma<256, 256, true, true, true><<<dim3(4, 64, 8), dim3(256), 0, stream>>>(tl, wp_tlo, s_tlo, b_tlo, d_out);

    // br chain (reuses tl buffer; pads still zero)
    conv3_mfma<128, 256, false, false, true><<<dim3(4, 64, 8), dim3(256), 0, stream>>>(bb, wp_br3, s_br3, b_br3, tl);
    conv1_mfma<<<dim3(2, 128, 8), dim3(256), 0, stream>>>(xb, wp_br1, s_br1, b_br1, tl);
    conv3_mfma<256, 256, true, true, true><<<dim3(4, 64, 8), dim3(256), 0, stream>>>(tl, wp_bro, s_bro, b_bro,
                                                                                     (float*)d_out + 33554432);
}

// Round 9
// 882.152 us; speedup vs baseline: 1.3638x; 1.0483x over previous
//
#include <hip/hip_runtime.h>
#include <cstdint>
#include <cstddef>

// B=8, C=256/128, H=W=128. Padded NHWC bf16 tensors: [n][130][130][C], pad ring = 0.
// elem(n,h,w,c) = ((n*130 + h+1)*130 + (w+1))*C + c
// All conv weights are prepacked with BN scale FOLDED IN (w *= s[oc]); epilogues add bias only.

typedef float  f32x4 __attribute__((ext_vector_type(4)));
typedef float  f4v   __attribute__((ext_vector_type(4)));
typedef short  s16x8 __attribute__((ext_vector_type(8)));
typedef unsigned short u16x4 __attribute__((ext_vector_type(4)));

__device__ __forceinline__ float bf2f(unsigned short u) {
    unsigned x = ((unsigned)u) << 16;
    return __builtin_bit_cast(float, x);
}
__device__ __forceinline__ unsigned short f2bf(float f) {
    unsigned u = __builtin_bit_cast(unsigned, f);
    unsigned r = (u + 0x7fffu + ((u >> 16) & 1u)) >> 16;
    return (unsigned short)r;
}

#define GL_LDS(gp, lp) __builtin_amdgcn_global_load_lds( \
    (const __attribute__((address_space(1))) unsigned int*)(const void*)(gp), \
    (__attribute__((address_space(3))) unsigned int*)(void*)(lp), 16, 0, 0)

// ---------------------------------------------------------------------------
// conv3x3 + bias (+opt ReLU), bf16 MFMA implicit GEMM. m4p4, 4 blk/CU,
// 2-phase dbuf pipeline. Bijective XCD swizzle. grid ((COUT/128)*2, 64, 8)
// ---------------------------------------------------------------------------
template<int CIN, int COUT, bool RELU, bool OUTF32, bool SWZ>
__global__ __launch_bounds__(256, 4)
void conv3_mfma(const unsigned short* __restrict__ in,
                const unsigned short* __restrict__ wpk,
                const float* __restrict__ bi,
                void* __restrict__ outv)
{
    __shared__ unsigned short lds[2][8704];      // 2 x 17408 B
    const int tid  = threadIdx.x;
    const int lane = tid & 63;
    const int wv   = tid >> 6;
    const int c    = lane & 15;
    const int g    = lane >> 4;

    constexpr int GX  = (COUT / 128) * 2;
    int gx, hy, n;
    if (SWZ) {
        constexpr int NWG = GX * 64 * 8;
        constexpr int Q   = NWG / 8;
        const int braw = blockIdx.x + GX * (blockIdx.y + 64 * blockIdx.z);
        const int wl   = (braw & 7) * Q + (braw >> 3);
        gx = wl % GX;
        const int rest = wl / GX;
        hy = rest & 63;
        n  = rest >> 6;
    } else {
        gx = blockIdx.x; hy = blockIdx.y; n = blockIdx.z;
    }
    const int wtile  = gx & 1;
    const int octile = gx >> 1;
    const int h0   = hy * 2;
    const int w0   = wtile * 64;
    const int r    = wv >> 1;
    const int ocbase = octile * 128 + (wv & 1) * 64;
    const int ocf0   = octile * 8 + (wv & 1) * 4;

    int addrB[3];
    #pragma unroll
    for (int kx = 0; kx < 3; ++kx) {
        int ps0 = c + kx;
        addrB[kx] = r * 4224 + ps0 * 64 + ((g ^ ((ps0 >> 1) & 3)) << 4);
    }

    int so[5];
    #pragma unroll
    for (int it = 0; it < 5; ++it) {
        int u   = it * 256 + tid;
        int row = u / 264;
        int rem = u - row * 264;
        int ps  = rem >> 2;
        int s   = rem & 3;
        int icq = s ^ ((ps >> 1) & 3);
        so[it] = ((n * 130 + h0 + row) * 130 + (w0 + ps)) * CIN + icq * 8;
    }

    auto STAGE = [&](int chunk, int bsel) {
        const unsigned short* bp = in + chunk * 32;
        char* lb = (char*)lds + bsel * 17408 + tid * 16;
        #pragma unroll
        for (int it = 0; it < 4; ++it)
            GL_LDS(bp + so[it], lb + it * 4096);
        if (wv == 0)
            GL_LDS(bp + so[4], lb + 16384);
    };

    f32x4 acc[4][4];
    #pragma unroll
    for (int m = 0; m < 4; ++m)
        #pragma unroll
        for (int p = 0; p < 4; ++p) acc[m][p] = 0.0f;

    const int NC = CIN / 32;
    STAGE(0, 0);
    __syncthreads();

    for (int chunk = 0; chunk < NC; ++chunk) {
        const int cur = chunk & 1;
        if (chunk + 1 < NC) STAGE(chunk + 1, cur ^ 1);
        const char* lb = (const char*)lds + cur * 17408;
        #pragma unroll
        for (int kk = 0; kk < 9; ++kk) {
            const int ky = kk / 3, kx = kk % 3;
            s16x8 af[4], bf[4];
            #pragma unroll
            for (int m = 0; m < 4; ++m)
                af[m] = *(const s16x8*)(wpk
                    + ((size_t)((chunk * 9 + kk) * (COUT / 16) + ocf0 + m)) * 512 + lane * 8);
            #pragma unroll
            for (int p = 0; p < 4; ++p)
                bf[p] = *(const s16x8*)(lb + addrB[kx] + ky * 4224 + p * 1024);
            #pragma unroll
            for (int m = 0; m < 4; ++m)
                #pragma unroll
                for (int p = 0; p < 4; ++p)
                    acc[m][p] = __builtin_amdgcn_mfma_f32_16x16x32_bf16(af[m], bf[p], acc[m][p], 0, 0, 0);
        }
        __syncthreads();
    }

    #pragma unroll
    for (int m = 0; m < 4; ++m) {
        const int oc4 = ocbase + m * 16 + g * 4;
        const f4v b4 = *(const f4v*)(bi + oc4);
        #pragma unroll
        for (int p = 0; p < 4; ++p) {
            const int w = w0 + p * 16 + c;
            float y[4];
            #pragma unroll
            for (int j = 0; j < 4; ++j) {
                y[j] = acc[m][p][j] + b4[j];
                if (RELU) y[j] = fmaxf(y[j], 0.0f);
            }
            if (OUTF32) {
                float* op = (float*)outv + (((size_t)n * COUT + oc4) << 14) + ((h0 + r) << 7) + w;
                op[0] = y[0]; op[16384] = y[1]; op[32768] = y[2]; op[49152] = y[3];
            } else {
                u16x4 pk;
                #pragma unroll
                for (int j = 0; j < 4; ++j) pk[j] = f2bf(y[j]);
                *(u16x4*)((unsigned short*)outv
                    + ((size_t)(n * 130 + h0 + r + 1) * 130 + w + 1) * COUT + oc4) = pk;
            }
        }
    }
}

// ---------------------------------------------------------------------------
// MERGED stage-A: t,l,b,r in ONE dispatch, XCD-grouped (round-8 proven, 54%).
// grid (4096)
// ---------------------------------------------------------------------------
__global__ __launch_bounds__(256, 4)
void conv3_tlbr(const unsigned short* __restrict__ in,
                const unsigned short* __restrict__ wq0,
                const float* __restrict__ bA,
                unsigned short* __restrict__ tt0)
{
    __shared__ unsigned short lds[2][8704];
    const int tid  = threadIdx.x;
    const int lane = tid & 63;
    const int wv   = tid >> 6;
    const int c    = lane & 15;
    const int g    = lane >> 4;

    const int b  = blockIdx.x;
    const int x  = b & 7;
    const int t  = b >> 3;
    const int q  = t & 3;
    const int ts = x + 8 * (t >> 2);
    const int wtile = ts & 1;
    const int hy    = (ts >> 1) & 63;
    const int n     = ts >> 7;
    const int h0 = hy * 2;
    const int w0 = wtile * 64;
    const int r  = wv >> 1;
    const int ocbase = (wv & 1) * 64;
    const int ocf0   = (wv & 1) * 4;

    const unsigned short* wpk = wq0 + q * 294912;
    const int outoff = ((q & 1) << 1) | (q >> 1);          // 0,2,1,3
    unsigned short* outv = tt0 + (size_t)outoff * ((size_t)8 * 130 * 130 * 128);
    const float* bi = bA + q * 128;

    int addrB[3];
    #pragma unroll
    for (int kx = 0; kx < 3; ++kx) {
        int ps0 = c + kx;
        addrB[kx] = r * 4224 + ps0 * 64 + ((g ^ ((ps0 >> 1) & 3)) << 4);
    }

    int so[5];
    #pragma unroll
    for (int it = 0; it < 5; ++it) {
        int u   = it * 256 + tid;
        int row = u / 264;
        int rem = u - row * 264;
        int ps  = rem >> 2;
        int s   = rem & 3;
        int icq = s ^ ((ps >> 1) & 3);
        so[it] = ((n * 130 + h0 + row) * 130 + (w0 + ps)) * 256 + icq * 8;
    }

    auto STAGE = [&](int chunk, int bsel) {
        const unsigned short* bp = in + chunk * 32;
        char* lb = (char*)lds + bsel * 17408 + tid * 16;
        #pragma unroll
        for (int it = 0; it < 4; ++it)
            GL_LDS(bp + so[it], lb + it * 4096);
        if (wv == 0)
            GL_LDS(bp + so[4], lb + 16384);
    };

    f32x4 acc[4][4];
    #pragma unroll
    for (int m = 0; m < 4; ++m)
        #pragma unroll
        for (int p = 0; p < 4; ++p) acc[m][p] = 0.0f;

    STAGE(0, 0);
    __syncthreads();

    for (int chunk = 0; chunk < 8; ++chunk) {
        const int cur = chunk & 1;
        if (chunk + 1 < 8) STAGE(chunk + 1, cur ^ 1);
        const char* lb = (const char*)lds + cur * 17408;
        #pragma unroll
        for (int kk = 0; kk < 9; ++kk) {
            const int ky = kk / 3, kx = kk % 3;
            s16x8 af[4], bf[4];
            #pragma unroll
            for (int m = 0; m < 4; ++m)
                af[m] = *(const s16x8*)(wpk
                    + ((size_t)((chunk * 9 + kk) * 8 + ocf0 + m)) * 512 + lane * 8);
            #pragma unroll
            for (int p = 0; p < 4; ++p)
                bf[p] = *(const s16x8*)(lb + addrB[kx] + ky * 4224 + p * 1024);
            #pragma unroll
            for (int m = 0; m < 4; ++m)
                #pragma unroll
                for (int p = 0; p < 4; ++p)
                    acc[m][p] = __builtin_amdgcn_mfma_f32_16x16x32_bf16(af[m], bf[p], acc[m][p], 0, 0, 0);
        }
        __syncthreads();
    }

    #pragma unroll
    for (int m = 0; m < 4; ++m) {
        const int oc4 = ocbase + m * 16 + g * 4;
        const f4v b4 = *(const f4v*)(bi + oc4);
        #pragma unroll
        for (int p = 0; p < 4; ++p) {
            const int w = w0 + p * 16 + c;
            u16x4 pk;
            #pragma unroll
            for (int j = 0; j < 4; ++j)
                pk[j] = f2bf(fmaxf(acc[m][p][j] + b4[j], 0.0f));
            *(u16x4*)(outv + ((size_t)(n * 130 + h0 + r + 1) * 130 + w + 1) * 128 + oc4) = pk;
        }
    }
}

// ---------------------------------------------------------------------------
// FUSED chain head, tl & br merged:
//   q=0: tl = relu(conv3(u1;w_tl3') + conv1(xb;w_tl1') + bsum_tl)  -> outTL
//   q=1: br = relu(conv3(u2;w_br3') + conv1(xb;w_br1') + bsum_br)  -> outBR
// 8 phases: 4x conv3 chunk (CIN=128) + 4x conv1 chunk-pair (2x32 ic).
// XCD map: b&7 = XCD; within XCD q fastest, then gx -> xb/u tiles L2-shared.
// grid (4096)
// ---------------------------------------------------------------------------
__global__ __launch_bounds__(256, 4)
void conv3p1_k(const unsigned short* __restrict__ u0,    // tt; bb at +T128
               const unsigned short* __restrict__ xb,
               const unsigned short* __restrict__ w30,   // wp_tl3; wp_br3 at +294912
               const unsigned short* __restrict__ w10,   // wp_tl1; wp_br1 at +65536
               const float* __restrict__ bsum0,          // [0..255]=tl, [256..511]=br
               unsigned short* __restrict__ outTL,
               unsigned short* __restrict__ outBR)
{
    __shared__ unsigned short lds[2][8704];
    const int tid  = threadIdx.x;
    const int lane = tid & 63;
    const int wv   = tid >> 6;
    const int c    = lane & 15;
    const int g    = lane >> 4;

    const int b  = blockIdx.x;
    const int x  = b & 7;
    const int s  = b >> 3;           // 0..511
    const int q  = s & 1;
    const int gx = (s >> 1) & 3;
    const int sp = x + 8 * (s >> 3); // 0..511
    const int hy = sp & 63;
    const int n  = sp >> 6;
    const int wtile  = gx & 1;
    const int octile = gx >> 1;
    const int h0 = hy * 2;
    const int w0 = wtile * 64;
    const int r  = wv >> 1;
    const int ocbase = octile * 128 + (wv & 1) * 64;
    const int ocf0   = octile * 8 + (wv & 1) * 4;

    const unsigned short* in3 = u0 + (size_t)q * ((size_t)8 * 130 * 130 * 128);
    const unsigned short* w3  = w30 + q * 294912;
    const unsigned short* w1  = w10 + q * 65536;
    const float* bi = bsum0 + q * 256;
    unsigned short* outv = q ? outBR : outTL;

    // conv3 B-read bases (proven)
    int addrB[3];
    #pragma unroll
    for (int kx = 0; kx < 3; ++kx) {
        int ps0 = c + kx;
        addrB[kx] = r * 4224 + ps0 * 64 + ((g ^ ((ps0 >> 1) & 3)) << 4);
    }
    // conv1 B-read base: [row r][px=16p+c][32 ic], rowstride 4096, XOR p-independent
    const int addrC1 = r * 4096 + c * 64 + ((g ^ ((c >> 1) & 3)) << 4);

    // conv3 staging offsets (CIN=128)
    int so3[5];
    #pragma unroll
    for (int it = 0; it < 5; ++it) {
        int u   = it * 256 + tid;
        int row = u / 264;
        int rem = u - row * 264;
        int ps  = rem >> 2;
        int ss  = rem & 3;
        int icq = ss ^ ((ps >> 1) & 3);
        so3[it] = ((n * 130 + h0 + row) * 130 + (w0 + ps)) * 128 + icq * 8;
    }
    // conv1 staging offsets: 1024 units = 2 chunks x [2 rows][64 px][4 x 8ic]
    int so1[4];
    #pragma unroll
    for (int it = 0; it < 4; ++it) {
        int u   = it * 256 + tid;
        int sub = u >> 9;
        int v   = u & 511;
        int row = v >> 8;
        int rem = v & 255;
        int px  = rem >> 2;
        int ss  = rem & 3;
        int icq = ss ^ ((px >> 1) & 3);
        so1[it] = ((n * 130 + h0 + 1 + row) * 130 + (w0 + px + 1)) * 256 + sub * 32 + icq * 8;
    }

    auto STAGE3 = [&](int chunk, int bsel) {
        const unsigned short* bp = in3 + chunk * 32;
        char* lb = (char*)lds + bsel * 17408 + tid * 16;
        #pragma unroll
        for (int it = 0; it < 4; ++it)
            GL_LDS(bp + so3[it], lb + it * 4096);
        if (wv == 0)
            GL_LDS(bp + so3[4], lb + 16384);
    };
    auto STAGE1 = [&](int j, int bsel) {      // stages conv1 chunks 2j, 2j+1
        const unsigned short* bp = xb + j * 64;
        char* lb = (char*)lds + bsel * 17408 + tid * 16;
        #pragma unroll
        for (int it = 0; it < 4; ++it)
            GL_LDS(bp + so1[it], lb + it * 4096);
    };

    f32x4 acc[4][4];
    #pragma unroll
    for (int m = 0; m < 4; ++m)
        #pragma unroll
        for (int p = 0; p < 4; ++p) acc[m][p] = 0.0f;

    STAGE3(0, 0);
    __syncthreads();

    for (int ph = 0; ph < 8; ++ph) {
        const int cur = ph & 1;
        if (ph < 3)      STAGE3(ph + 1, cur ^ 1);
        else if (ph < 7) STAGE1(ph - 3, cur ^ 1);
        const char* lb = (const char*)lds + cur * 17408;
        if (ph < 4) {
            #pragma unroll
            for (int kk = 0; kk < 9; ++kk) {
                const int ky = kk / 3, kx = kk % 3;
                s16x8 af[4], bf[4];
                #pragma unroll
                for (int m = 0; m < 4; ++m)
                    af[m] = *(const s16x8*)(w3
                        + ((size_t)((ph * 9 + kk) * 16 + ocf0 + m)) * 512 + lane * 8);
                #pragma unroll
                for (int p = 0; p < 4; ++p)
                    bf[p] = *(const s16x8*)(lb + addrB[kx] + ky * 4224 + p * 1024);
                #pragma unroll
                for (int m = 0; m < 4; ++m)
                    #pragma unroll
                    for (int p = 0; p < 4; ++p)
                        acc[m][p] = __builtin_amdgcn_mfma_f32_16x16x32_bf16(af[m], bf[p], acc[m][p], 0, 0, 0);
            }
        } else {
            const int j = ph - 4;
            #pragma unroll
            for (int sub = 0; sub < 2; ++sub) {
                s16x8 af[4], bf[4];
                #pragma unroll
                for (int m = 0; m < 4; ++m)
                    af[m] = *(const s16x8*)(w1
                        + ((size_t)(((j * 2 + sub) * 16) + ocf0 + m)) * 512 + lane * 8);
                #pragma unroll
                for (int p = 0; p < 4; ++p)
                    bf[p] = *(const s16x8*)(lb + sub * 8192 + addrC1 + p * 1024);
                #pragma unroll
                for (int m = 0; m < 4; ++m)
                    #pragma unroll
                    for (int p = 0; p < 4; ++p)
                        acc[m][p] = __builtin_amdgcn_mfma_f32_16x16x32_bf16(af[m], bf[p], acc[m][p], 0, 0, 0);
            }
        }
        __syncthreads();
    }

    #pragma unroll
    for (int m = 0; m < 4; ++m) {
        const int oc4 = ocbase + m * 16 + g * 4;
        const f4v b4 = *(const f4v*)(bi + oc4);
        #pragma unroll
        for (int p = 0; p < 4; ++p) {
            const int w = w0 + p * 16 + c;
            u16x4 pk;
            #pragma unroll
            for (int j = 0; j < 4; ++j)
                pk[j] = f2bf(fmaxf(acc[m][p][j] + b4[j], 0.0f));
            *(u16x4*)(outv + ((size_t)(n * 130 + h0 + r + 1) * 130 + w + 1) * 256 + oc4) = pk;
        }
    }
}

// ---------------------------------------------------------------------------
// fused H-pools (8-deep batching): even blk: ta=revcummaxH; odd: tb=cummaxH
// ---------------------------------------------------------------------------
__global__ __launch_bounds__(128)
void pool_h2_k(unsigned short* __restrict__ ta, unsigned short* __restrict__ tb)
{
    const int sel = blockIdx.x & 1;
    const int col = blockIdx.x >> 1;
    unsigned short* p = sel ? tb : ta;
    const int n = col >> 7, w = col & 127, cth = threadIdx.x;
    unsigned short* base = p + (((size_t)n * 130 + 1) * 130 + (w + 1)) * 128 + cth;
    const int stride = 130 * 128;
    float m = -3.402823466e+38f;
    if (sel == 0) {
        for (int gq = 0; gq < 16; ++gq) {
            const int h0 = 127 - gq * 8;
            float v[8];
            #pragma unroll
            for (int j = 0; j < 8; ++j) v[j] = bf2f(base[(size_t)(h0 - j) * stride]);
            unsigned short o[8];
            #pragma unroll
            for (int j = 0; j < 8; ++j) { m = fmaxf(m, v[j]); o[j] = f2bf(m); }
            #pragma unroll
            for (int j = 0; j < 8; ++j) base[(size_t)(h0 - j) * stride] = o[j];
        }
    } else {
        for (int gq = 0; gq < 16; ++gq) {
            const int h0 = gq * 8;
            float v[8];
            #pragma unroll
            for (int j = 0; j < 8; ++j) v[j] = bf2f(base[(size_t)(h0 + j) * stride]);
            unsigned short o[8];
            #pragma unroll
            for (int j = 0; j < 8; ++j) { m = fmaxf(m, v[j]); o[j] = f2bf(m); }
            #pragma unroll
            for (int j = 0; j < 8; ++j) base[(size_t)(h0 + j) * stride] = o[j];
        }
    }
}

// ---------------------------------------------------------------------------
// fused W-pools + add: even blk: ta += revcummaxW(la); odd: tb += cummaxW(lb)
// ---------------------------------------------------------------------------
__global__ __launch_bounds__(128)
void pool_w_add2_k(const unsigned short* __restrict__ la, unsigned short* __restrict__ ta,
                   const unsigned short* __restrict__ lb, unsigned short* __restrict__ tb)
{
    const int sel = blockIdx.x & 1;
    const int row = blockIdx.x >> 1;
    const unsigned short* ls = sel ? lb : la;
    unsigned short* td = sel ? tb : ta;
    const int n = row >> 7, hh = row & 127, cth = threadIdx.x;
    const size_t rowbase = ((size_t)(n * 130 + hh + 1) * 130) * 128 + cth;
    float m = -3.402823466e+38f;
    if (sel == 0) {
        for (int gq = 0; gq < 16; ++gq) {
            const int w0 = 127 - gq * 8;
            float lv[8], tv[8];
            #pragma unroll
            for (int j = 0; j < 8; ++j) {
                size_t off = rowbase + (size_t)(w0 - j + 1) * 128;
                lv[j] = bf2f(ls[off]); tv[j] = bf2f(td[off]);
            }
            unsigned short o[8];
            #pragma unroll
            for (int j = 0; j < 8; ++j) { m = fmaxf(m, lv[j]); o[j] = f2bf(m + tv[j]); }
            #pragma unroll
            for (int j = 0; j < 8; ++j) td[rowbase + (size_t)(w0 - j + 1) * 128] = o[j];
        }
    } else {
        for (int gq = 0; gq < 16; ++gq) {
            const int w0 = gq * 8;
            float lv[8], tv[8];
            #pragma unroll
            for (int j = 0; j < 8; ++j) {
                size_t off = rowbase + (size_t)(w0 + j + 1) * 128;
                lv[j] = bf2f(ls[off]); tv[j] = bf2f(td[off]);
            }
            unsigned short o[8];
            #pragma unroll
            for (int j = 0; j < 8; ++j) { m = fmaxf(m, lv[j]); o[j] = f2bf(m + tv[j]); }
            #pragma unroll
            for (int j = 0; j < 8; ++j) td[rowbase + (size_t)(w0 + j + 1) * 128] = o[j];
        }
    }
}

// ---------------------------------------------------------------------------
// pad-ring zero, single tensor (tl re-pad after pools)
// ---------------------------------------------------------------------------
__global__ __launch_bounds__(256)
void padzero_k(unsigned short* __restrict__ t, int C)
{
    int idx = blockIdx.x * 256 + threadIdx.x;
    int n = blockIdx.y;
    int cpu = C >> 3;
    if (idx >= 516 * cpu) return;
    int cell = idx / cpu, cq = idx - cell * cpu;
    int h, w;
    if (cell < 260) { h = (cell < 130) ? -1 : 128; w = (cell % 130) - 1; }
    else { int j = cell - 260; w = (j < 128) ? -1 : 128; h = j & 127; }
    size_t off = (((size_t)n * 130 + h + 1) * 130 + (w + 1)) * C + cq * 8;
    uint4 z; z.x = 0; z.y = 0; z.z = 0; z.w = 0;
    *(uint4*)(t + off) = z;
}

// ---------------------------------------------------------------------------
// merged pad-ring zero for 6 tensors (xb 256, tt/bb/ll/rr 128, pbr 256).
// grid (516, 6, 8)
// ---------------------------------------------------------------------------
__global__ __launch_bounds__(256)
void padzero_all_k(unsigned short* xb, unsigned short* tt, unsigned short* bb,
                   unsigned short* ll, unsigned short* rr, unsigned short* pbr)
{
    const int id = blockIdx.y;
    unsigned short* t = id == 0 ? xb : (id == 1 ? tt : (id == 2 ? bb :
                        (id == 3 ? ll : (id == 4 ? rr : pbr))));
    const int C = (id == 0 || id == 5) ? 256 : 128;
    int idx = blockIdx.x * 256 + threadIdx.x;
    int n = blockIdx.z;
    int cpu = C >> 3;
    if (idx >= 516 * cpu) return;
    int cell = idx / cpu, cq = idx - cell * cpu;
    int h, w;
    if (cell < 260) { h = (cell < 130) ? -1 : 128; w = (cell % 130) - 1; }
    else { int j = cell - 260; w = (j < 128) ? -1 : 128; h = j & 127; }
    size_t off = (((size_t)n * 130 + h + 1) * 130 + (w + 1)) * C + cq * 8;
    uint4 z; z.x = 0; z.y = 0; z.z = 0; z.w = 0;
    *(uint4*)(t + off) = z;
}

// ---------------------------------------------------------------------------
// x fp32 NCHW -> bf16 NHWC padded interior. grid (128 h, 8 n)
// ---------------------------------------------------------------------------
__global__ __launch_bounds__(256)
void transform_x_k(const float* __restrict__ x, unsigned short* __restrict__ xb)
{
    __shared__ float sm[64][132];
    const int h = blockIdx.x, n = blockIdx.y, t = threadIdx.x;
    for (int cc0 = 0; cc0 < 256; cc0 += 64) {
        __syncthreads();
        {
            int ci = t >> 7, wi = t & 127;
            #pragma unroll 8
            for (int k = 0; k < 32; ++k)
                sm[ci + 2 * k][wi] = x[((size_t)(n * 256 + cc0 + ci + 2 * k) << 14) + (h << 7) + wi];
        }
        __syncthreads();
        {
            int wi = t >> 1, cq = t & 1;
            unsigned short tmp[32];
            #pragma unroll
            for (int m2 = 0; m2 < 32; ++m2) tmp[m2] = f2bf(sm[cq * 32 + m2][wi]);
            unsigned short* dst = xb + (((size_t)n * 130 + h + 1) * 130 + wi + 1) * 256 + cc0 + cq * 32;
            #pragma unroll
            for (int q = 0; q < 4; ++q) *(uint4*)(dst + q * 8) = *(const uint4*)(tmp + q * 8);
        }
    }
}

// ---------------------------------------------------------------------------
// merged prepack: 8x conv3 + 2x conv1 (scale folded in) + bias concats.
// grid (2304, 11)
// ---------------------------------------------------------------------------
struct PrepArgs {
    const float* w[10];          // t,l,b,r,tl3,br3,tlo,bro,tl1,br1
    unsigned short* dst[10];
    const float* s[10];          // matching scales (folded into w)
    const float* bv[4];          // b_t,b_l,b_b,b_r
    const float* bx[4];          // b_tl3,b_tl1,b_br3,b_br1
    float* bA; float* bsum;      // bA[512] stage-A; bsum[512] = {tl3+tl1, br3+br1}
};

__global__ __launch_bounds__(256)
void prepack_all_k(PrepArgs a)
{
    const int id = blockIdx.y;
    int idx = blockIdx.x * 256 + threadIdx.x;
    if (id == 10) {
        if (idx < 512) a.bA[idx] = a.bv[idx >> 7][idx & 127];
        else if (idx < 768)  { int i = idx - 512; a.bsum[i]       = a.bx[0][i] + a.bx[1][i]; }
        else if (idx < 1024) { int i = idx - 768; a.bsum[256 + i] = a.bx[2][i] + a.bx[3][i]; }
        return;
    }
    if (id >= 8) {                        // conv1 prepack (256x256), scale folded
        if (idx >= 65536) return;
        int ic = idx & 255, oc = idx >> 8;
        float v = a.w[id][oc * 256 + ic] * a.s[id][oc];
        int chunk = ic >> 5, icr = ic & 31, gg = icr >> 3, j = icr & 7;
        int m = oc >> 4, ocr = oc & 15, ln = gg * 16 + ocr;
        a.dst[id][((size_t)(chunk * 16 + m)) * 512 + ln * 8 + j] = f2bf(v);
        return;
    }
    const int CIN  = (id < 4) ? 256 : ((id < 6) ? 128 : 256);
    const int COUT = (id < 4) ? 128 : 256;
    if (idx >= COUT * CIN * 9) return;
    int kk = idx % 9; int rest = idx / 9;
    int ic = rest % CIN; int oc = rest / CIN;
    float v = a.w[id][(size_t)(oc * CIN + ic) * 9 + kk] * a.s[id][oc];
    int chunk = ic >> 5, icr = ic & 31, gg = icr >> 3, j = icr & 7;
    int m = oc >> 4, ocr = oc & 15, ln = gg * 16 + ocr;
    a.dst[id][((size_t)((chunk * 9 + kk) * (COUT / 16) + m)) * 512 + ln * 8 + j] = f2bf(v);
}

// ---------------------------------------------------------------------------
extern "C" void kernel_launch(void* const* d_in, const int* in_sizes, int n_in,
                              void* d_out, int out_size, void* d_ws, size_t ws_size,
                              hipStream_t stream)
{
    const float* x     = (const float*)d_in[0];
    const float* w_t   = (const float*)d_in[1];
    const float* s_t   = (const float*)d_in[2];
    const float* b_t   = (const float*)d_in[3];
    const float* w_l   = (const float*)d_in[4];
    const float* s_l   = (const float*)d_in[5];
    const float* b_l   = (const float*)d_in[6];
    const float* w_b   = (const float*)d_in[7];
    const float* s_b   = (const float*)d_in[8];
    const float* b_b   = (const float*)d_in[9];
    const float* w_r   = (const float*)d_in[10];
    const float* s_r   = (const float*)d_in[11];
    const float* b_r   = (const float*)d_in[12];
    const float* w_tl3 = (const float*)d_in[13];
    const float* s_tl3 = (const float*)d_in[14];
    const float* b_tl3 = (const float*)d_in[15];
    const float* w_br3 = (const float*)d_in[16];
    const float* s_br3 = (const float*)d_in[17];
    const float* b_br3 = (const float*)d_in[18];
    const float* w_tl1 = (const float*)d_in[19];
    const float* s_tl1 = (const float*)d_in[20];
    const float* b_tl1 = (const float*)d_in[21];
    const float* w_br1 = (const float*)d_in[22];
    const float* s_br1 = (const float*)d_in[23];
    const float* b_br1 = (const float*)d_in[24];
    const float* w_tlo = (const float*)d_in[25];
    const float* s_tlo = (const float*)d_in[26];
    const float* b_tlo = (const float*)d_in[27];
    const float* w_bro = (const float*)d_in[28];
    const float* s_bro = (const float*)d_in[29];
    const float* b_bro = (const float*)d_in[30];

    typedef unsigned short ush;
    const size_t T256 = (size_t)8 * 130 * 130 * 256;
    const size_t T128 = (size_t)8 * 130 * 130 * 128;

    ush* xb = (ush*)d_ws;
    ush* tt = xb + T256;
    ush* bb = tt + T128;
    ush* ll = bb + T128;
    ush* rr = ll + T128;
    ush* wq = rr + T128;
    ush* wp_t   = wq;                    // 4x 294912 contiguous (stage A, q-indexed)
    ush* wp_l   = wp_t   + 294912;
    ush* wp_b   = wp_l   + 294912;
    ush* wp_r   = wp_b   + 294912;
    ush* wp_tl3 = wp_r   + 294912;       // tl3, br3 contiguous
    ush* wp_br3 = wp_tl3 + 294912;
    ush* wp_tlo = wp_br3 + 294912;
    ush* wp_bro = wp_tlo + 589824;
    ush* wp_tl1 = wp_bro + 589824;       // tl1, br1 contiguous
    ush* wp_br1 = wp_tl1 + 65536;
    float* bA   = (float*)(wp_br1 + 65536);  // 512 f
    float* bsum = bA + 512;                  // 512 f
    ush* tl  = ll;                           // 256-ch buffer over ll+rr
    ush* pbr = (ush*)d_out;                  // P_br staging in d_out 1st half

    PrepArgs pa;
    pa.w[0] = w_t;  pa.w[1] = w_l;  pa.w[2] = w_b;  pa.w[3] = w_r;
    pa.w[4] = w_tl3; pa.w[5] = w_br3; pa.w[6] = w_tlo; pa.w[7] = w_bro;
    pa.w[8] = w_tl1; pa.w[9] = w_br1;
    pa.dst[0] = wp_t;  pa.dst[1] = wp_l;  pa.dst[2] = wp_b;  pa.dst[3] = wp_r;
    pa.dst[4] = wp_tl3; pa.dst[5] = wp_br3; pa.dst[6] = wp_tlo; pa.dst[7] = wp_bro;
    pa.dst[8] = wp_tl1; pa.dst[9] = wp_br1;
    pa.s[0] = s_t;  pa.s[1] = s_l;  pa.s[2] = s_b;  pa.s[3] = s_r;
    pa.s[4] = s_tl3; pa.s[5] = s_br3; pa.s[6] = s_tlo; pa.s[7] = s_bro;
    pa.s[8] = s_tl1; pa.s[9] = s_br1;
    pa.bv[0] = b_t; pa.bv[1] = b_l; pa.bv[2] = b_b; pa.bv[3] = b_r;
    pa.bx[0] = b_tl3; pa.bx[1] = b_tl1; pa.bx[2] = b_br3; pa.bx[3] = b_br1;
    pa.bA = bA; pa.bsum = bsum;
    prepack_all_k<<<dim3(2304, 11), dim3(256), 0, stream>>>(pa);
    padzero_all_k<<<dim3(516, 6, 8), dim3(256), 0, stream>>>(xb, tt, bb, ll, rr, pbr);
    transform_x_k<<<dim3(128, 8), dim3(256), 0, stream>>>(x, xb);

    // stage A: t,l,b,r merged, XCD-tile-grouped
    conv3_tlbr<<<dim3(4096), dim3(256), 0, stream>>>(xb, wp_t, bA, tt);

    // pools: u1 = revcummaxH(tt)+revcummaxW(ll); u2 = cummaxH(bb)+cummaxW(rr)
    pool_h2_k<<<dim3(2048), dim3(128), 0, stream>>>(tt, bb);
    pool_w_add2_k<<<dim3(2048), dim3(128), 0, stream>>>(ll, tt, rr, bb);

    // fused chain heads: tl -> tl buffer, br -> d_out 1st half (P_br)
    padzero_k<<<dim3(66, 8), dim3(256), 0, stream>>>(tl, 256);
    conv3p1_k<<<dim3(4096), dim3(256), 0, stream>>>(tt, xb, wp_tl3, wp_tl1, bsum, tl, pbr);

    // bro first (reads P_br from 1st half, writes 2nd half), then tlo
    // (overwrites 1st half after P_br is dead)
    conv3_mfma<256, 256, true, true, true><<<dim3(4, 64, 8), dim3(256), 0, stream>>>(
        pbr, wp_bro, b_bro, (float*)d_out + 33554432);
    conv3_mfma<256, 256, true, true, true><<<dim3(4, 64, 8), dim3(256), 0, stream>>>(
        tl, wp_tlo, b_tlo, d_out);
}